// Round 1
// baseline (5127.946 us; speedup 1.0000x reference)
//
#include <hip/hip_runtime.h>
#include <math.h>

#define D_ 512
#define H_ 8

// ---------------- utility ----------------
__global__ void fill_kernel(float* __restrict__ p, float v, long n) {
  long i = (long)blockIdx.x * blockDim.x + threadIdx.x;
  long st = (long)gridDim.x * blockDim.x;
  for (; i < n; i += st) p[i] = v;
}

__device__ __forceinline__ void atomic_add_f(float* p, float v) {
  unsafeAtomicAdd(p, v);  // hardware global_atomic_add_f32 on gfx950
}

__device__ __forceinline__ void atomic_max_f(float* addr, float val) {
  int* ai = (int*)addr;
  int old = __float_as_int(*addr);
  while (__int_as_float(old) < val) {
    int assumed = old;
    old = atomicCAS(ai, assumed, __float_as_int(val));
    if (old == assumed) break;
  }
}

// ---------------- fused weight precompute ----------------
// Wf[c][h*64+e] = sum_d Win[c][h*64+d] * rel[h][d][e];  row 512 == bias row
__global__ void fuse_weight_kernel(const float* __restrict__ Win,
                                   const float* __restrict__ bin,
                                   const float* __restrict__ rel,
                                   float* __restrict__ Wf,
                                   float* __restrict__ bf) {
  int row = blockIdx.x;            // 0..512
  int j = threadIdx.x;             // 0..511
  int h = j >> 6, e = j & 63;
  const float* src = (row < D_) ? (Win + (long)row * D_) : bin;
  const float* rl = rel + h * 64 * 64;
  float acc = 0.f;
#pragma unroll 16
  for (int d = 0; d < 64; ++d) acc = fmaf(src[h * 64 + d], rl[d * 64 + e], acc);
  if (row < D_) Wf[(long)row * D_ + j] = acc;
  else bf[j] = acc;
}

// ---------------- GEMM: C[Mx512] = A[Mx512] @ W[512x512] + bias ----------------
// WITH_SKIP: C = (acc*a_scale + bias)*sigmoid(skip[idx]) + Hres*(1-sigmoid)
template <int WITH_SKIP>
__global__ void gemm_kernel(const float* __restrict__ A,
                            const float* __restrict__ W,
                            const float* __restrict__ bias,
                            float* __restrict__ C, int M, float a_scale,
                            const float* __restrict__ Hres,
                            const float* __restrict__ skip, int skip_idx) {
  __shared__ float As[16][64];
  __shared__ float Bs[16][64];
  const int bm = blockIdx.y * 64, bn = blockIdx.x * 64;
  const int tid = threadIdx.x;
  const int tm = (tid >> 4) << 2;
  const int tn = (tid & 15) << 2;
  float acc[4][4] = {};
  for (int k0 = 0; k0 < D_; k0 += 16) {
#pragma unroll
    for (int i = 0; i < 4; ++i) {
      int idx = tid + (i << 8);
      int r = idx >> 4, c = idx & 15;
      As[c][r] = (bm + r < M) ? A[(long)(bm + r) * D_ + k0 + c] : 0.f;
    }
#pragma unroll
    for (int i = 0; i < 4; ++i) {
      int idx = tid + (i << 8);
      int kk = idx >> 6, n = idx & 63;
      Bs[kk][n] = W[(long)(k0 + kk) * D_ + bn + n];
    }
    __syncthreads();
#pragma unroll
    for (int kk = 0; kk < 16; ++kk) {
      float a[4], b[4];
#pragma unroll
      for (int i = 0; i < 4; ++i) a[i] = As[kk][tm + i];
#pragma unroll
      for (int j = 0; j < 4; ++j) b[j] = Bs[kk][tn + j];
#pragma unroll
      for (int i = 0; i < 4; ++i)
#pragma unroll
        for (int j = 0; j < 4; ++j)
          acc[i][j] = fmaf(a[i], b[j], acc[i][j]);
    }
    __syncthreads();
  }
  float alpha = 0.f, beta = 0.f;
  if (WITH_SKIP) {
    float sv = skip[skip_idx];
    alpha = 1.f / (1.f + expf(-sv));
    beta = 1.f - alpha;
  }
#pragma unroll
  for (int i = 0; i < 4; ++i) {
    int r = bm + tm + i;
    if (r >= M) continue;
#pragma unroll
    for (int j = 0; j < 4; ++j) {
      int col = bn + tn + j;
      float val = acc[i][j] * a_scale + bias[col];
      if (WITH_SKIP) val = val * alpha + Hres[(long)r * D_ + col] * beta;
      C[(long)r * D_ + col] = val;
    }
  }
}

// ---------------- edge attention ----------------
// one 64-lane wave per edge; lane l -> head h=l>>3, 8 elems at (l&7)*8
__global__ void edge_score_kernel(const float* __restrict__ q,
                                  const float* __restrict__ k,
                                  const int* __restrict__ src,
                                  const int* __restrict__ dst,
                                  const float* __restrict__ pri,
                                  float* __restrict__ s, float* __restrict__ m,
                                  int E) {
  long gid = (long)blockIdx.x * blockDim.x + threadIdx.x;
  int e = (int)(gid >> 6);
  if (e >= E) return;
  int lane = (int)(gid & 63);
  int si = src[e], di = dst[e];
  int h = lane >> 3;
  int off = (lane & 7) << 3;
  const float4* q4 = (const float4*)(q + (long)di * D_ + h * 64 + off);
  const float4* k4 = (const float4*)(k + (long)si * D_ + h * 64 + off);
  float4 qa = q4[0], qb = q4[1], ka = k4[0], kb = k4[1];
  float acc = qa.x * ka.x + qa.y * ka.y + qa.z * ka.z + qa.w * ka.w +
              qb.x * kb.x + qb.y * kb.y + qb.z * kb.z + qb.w * kb.w;
  acc += __shfl_xor(acc, 1);
  acc += __shfl_xor(acc, 2);
  acc += __shfl_xor(acc, 4);
  if ((lane & 7) == 0) {
    float sc = acc * pri[h] * 0.125f;  // 1/sqrt(64)
    s[(long)e * H_ + h] = sc;
    atomic_max_f(m + (long)di * H_ + h, sc);
  }
}

__global__ void edge_exp_kernel(const int* __restrict__ dst,
                                float* __restrict__ s,
                                const float* __restrict__ m,
                                float* __restrict__ den, int E) {
  long i = (long)blockIdx.x * blockDim.x + threadIdx.x;
  if (i >= (long)E * H_) return;
  int e = (int)(i >> 3), h = (int)(i & 7);
  int di = dst[e];
  float ex = expf(s[i] - m[(long)di * H_ + h]);
  s[i] = ex;
  atomic_add_f(den + (long)di * H_ + h, ex);
}

__global__ void edge_agg_kernel(const float* __restrict__ v,
                                const int* __restrict__ src,
                                const int* __restrict__ dst,
                                const float* __restrict__ ex,
                                const float* __restrict__ den,
                                float* __restrict__ agg, int E) {
  long gid = (long)blockIdx.x * blockDim.x + threadIdx.x;
  int e = (int)(gid >> 6);
  if (e >= E) return;
  int lane = (int)(gid & 63);
  int si = src[e], di = dst[e];
  const float* vr = v + (long)si * D_;
  float* ar = agg + (long)di * D_;
#pragma unroll
  for (int h = 0; h < H_; ++h) {
    float a = ex[(long)e * H_ + h] / den[(long)di * H_ + h];
    atomic_add_f(ar + h * 64 + lane, vr[h * 64 + lane] * a);
  }
}

// ---------------- launch ----------------
extern "C" void kernel_launch(void* const* d_in, const int* in_sizes, int n_in,
                              void* d_out, int out_size, void* d_ws, size_t ws_size,
                              hipStream_t stream) {
  const float* h_author = (const float*)d_in[0];
  const float* h_paper  = (const float*)d_in[1];
  const int* w_src = (const int*)d_in[2];
  const int* w_dst = (const int*)d_in[3];
  const int* c_src = (const int*)d_in[4];
  const int* c_dst = (const int*)d_in[5];
  const int* b_src = (const int*)d_in[6];
  const int* b_dst = (const int*)d_in[7];
  const float* Wk = (const float*)d_in[8];
  const float* bk = (const float*)d_in[9];
  const float* Wq = (const float*)d_in[10];
  const float* bq = (const float*)d_in[11];
  const float* Wv = (const float*)d_in[12];
  const float* bv = (const float*)d_in[13];
  const float* Wa = (const float*)d_in[14];
  const float* ba = (const float*)d_in[15];
  const float* rel_att = (const float*)d_in[16];
  const float* rel_msg = (const float*)d_in[17];
  const float* rel_pri = (const float*)d_in[18];
  const float* skip = (const float*)d_in[19];

  const int NA = in_sizes[0] / D_;
  const int NP = in_sizes[1] / D_;
  const int E  = in_sizes[2];
  const long nmax = (NA > NP) ? NA : NP;

  float* ws = (float*)d_ws;
  float* qbuf = ws;
  float* kbuf = qbuf + nmax * D_;
  float* vbuf = kbuf + nmax * D_;
  float* tbuf = vbuf + nmax * D_;
  float* sbuf = tbuf + nmax * D_;
  float* mbuf = sbuf + (long)E * H_;
  float* dbuf = mbuf + nmax * H_;
  float* WfA  = dbuf + nmax * H_;
  float* bfA  = WfA + (long)D_ * D_;
  float* WfM  = bfA + D_;
  float* bfM  = WfM + (long)D_ * D_;

  const long WD = (long)D_ * D_;   // per-type weight stride
  const long RS = (long)H_ * 64 * 64;  // per-relation rel stride

  auto fill = [&](float* p, float v, long n) {
    long b = (n + 255) / 256;
    int blocks = (int)(b > 4096 ? 4096 : b);
    fill_kernel<<<blocks, 256, 0, stream>>>(p, v, n);
  };

#define GEMM(Aa, Ww, bb, Cc, Mm)                                            \
  gemm_kernel<0><<<dim3(8, ((Mm) + 63) / 64), 256, 0, stream>>>(            \
      (Aa), (Ww), (bb), (Cc), (Mm), 1.f, nullptr, nullptr, 0)
#define GEMM_SKIP(Aa, Ww, bb, Cc, Mm, sc, Hh, si)                           \
  gemm_kernel<1><<<dim3(8, ((Mm) + 63) / 64), 256, 0, stream>>>(            \
      (Aa), (Ww), (bb), (Cc), (Mm), (sc), (Hh), skip, (si))

  auto run_edges = [&](const float* qb, const int* es, const int* ed,
                       const float* pri, int ndst, float* agg) {
    fill(mbuf, -INFINITY, (long)ndst * H_);
    fill(dbuf, 0.f, (long)ndst * H_);
    long th1 = (long)E * 64;
    long th2 = (long)E * H_;
    edge_score_kernel<<<(int)((th1 + 255) / 256), 256, 0, stream>>>(
        qb, kbuf, es, ed, pri, sbuf, mbuf, E);
    edge_exp_kernel<<<(int)((th2 + 255) / 256), 256, 0, stream>>>(
        ed, sbuf, mbuf, dbuf, E);
    edge_agg_kernel<<<(int)((th1 + 255) / 256), 256, 0, stream>>>(
        vbuf, es, ed, sbuf, dbuf, agg, E);
  };

  float* out_a = (float*)d_out;
  float* out_p = out_a + (long)NA * D_;

  // q_p = h_paper @ Wq[1] + bq[1]
  GEMM(h_paper, Wq + WD, bq + D_, qbuf, NP);

  // ---- relation 0: writes (author -> paper) ----
  fuse_weight_kernel<<<513, 512, 0, stream>>>(Wk, bk, rel_att, WfA, bfA);
  fuse_weight_kernel<<<513, 512, 0, stream>>>(Wv, bv, rel_msg, WfM, bfM);
  GEMM(h_author, WfA, bfA, kbuf, NA);
  GEMM(h_author, WfM, bfM, vbuf, NA);
  fill(tbuf, 0.f, (long)NP * D_);
  run_edges(qbuf, w_src, w_dst, rel_pri, NP, tbuf);

  // ---- relation 1: cites (paper -> paper) ----
  fuse_weight_kernel<<<513, 512, 0, stream>>>(Wk + WD, bk + D_, rel_att + RS, WfA, bfA);
  fuse_weight_kernel<<<513, 512, 0, stream>>>(Wv + WD, bv + D_, rel_msg + RS, WfM, bfM);
  GEMM(h_paper, WfA, bfA, kbuf, NP);
  GEMM(h_paper, WfM, bfM, vbuf, NP);
  run_edges(qbuf, c_src, c_dst, rel_pri + H_, NP, tbuf);

  // ---- paper output: (0.5*t @ Wa[1] + ba[1]) mixed with h_paper ----
  GEMM_SKIP(tbuf, Wa + WD, ba + D_, out_p, NP, 0.5f, h_paper, 1);

  // q_a = h_author @ Wq[0] + bq[0]
  GEMM(h_author, Wq, bq, qbuf, NA);

  // ---- relation 2: written_by (paper -> author) ----
  fuse_weight_kernel<<<513, 512, 0, stream>>>(Wk + WD, bk + D_, rel_att + 2 * RS, WfA, bfA);
  fuse_weight_kernel<<<513, 512, 0, stream>>>(Wv + WD, bv + D_, rel_msg + 2 * RS, WfM, bfM);
  GEMM(h_paper, WfA, bfA, kbuf, NP);
  GEMM(h_paper, WfM, bfM, vbuf, NP);
  fill(tbuf, 0.f, (long)NA * D_);
  run_edges(qbuf, b_src, b_dst, rel_pri + 2 * H_, NA, tbuf);

  // ---- author output ----
  GEMM_SKIP(tbuf, Wa, ba, out_a, NA, 1.f, h_author, 0);

#undef GEMM
#undef GEMM_SKIP
}

// Round 2
// 1610.685 us; speedup vs baseline: 3.1837x; 3.1837x over previous
//
#include <hip/hip_runtime.h>
#include <math.h>

#define D_ 512
#define H_ 8

typedef short bf16x8 __attribute__((ext_vector_type(8)));
typedef float f32x4 __attribute__((ext_vector_type(4)));

__device__ __forceinline__ unsigned short f2bf(float x) {
  unsigned int u = __float_as_uint(x);
  unsigned int r = (u + 0x7fff + ((u >> 16) & 1)) >> 16;
  return (unsigned short)r;
}
__device__ __forceinline__ float bf2f(unsigned short b) {
  return __uint_as_float(((unsigned int)b) << 16);
}

// ---------------- utility ----------------
__global__ void fill_kernel(float* __restrict__ p, float v, long n) {
  long i = (long)blockIdx.x * blockDim.x + threadIdx.x;
  long st = (long)gridDim.x * blockDim.x;
  for (; i < n; i += st) p[i] = v;
}

__global__ void convert_bf16_kernel(const float* __restrict__ in,
                                    unsigned short* __restrict__ out, long n8) {
  long i = (long)blockIdx.x * blockDim.x + threadIdx.x;
  long st = (long)gridDim.x * blockDim.x;
  for (; i < n8; i += st) {
    float4 a = ((const float4*)in)[i * 2];
    float4 b = ((const float4*)in)[i * 2 + 1];
    bf16x8 o;
    o[0] = (short)f2bf(a.x); o[1] = (short)f2bf(a.y);
    o[2] = (short)f2bf(a.z); o[3] = (short)f2bf(a.w);
    o[4] = (short)f2bf(b.x); o[5] = (short)f2bf(b.y);
    o[6] = (short)f2bf(b.z); o[7] = (short)f2bf(b.w);
    ((bf16x8*)out)[i] = o;
  }
}

// Wt[n][k] = bf16(W[k][n]) for a 512x512 matrix
__global__ void transpose_bf16_kernel(const float* __restrict__ W,
                                      unsigned short* __restrict__ Wt) {
  int n = blockIdx.x;
  int k = threadIdx.x;
  Wt[(long)n * D_ + k] = f2bf(W[(long)k * D_ + n]);
}

__device__ __forceinline__ void atomic_add_f(float* p, float v) {
  unsafeAtomicAdd(p, v);  // hardware global_atomic_add_f32
}

__device__ __forceinline__ void atomic_max_f(float* addr, float val) {
  int* ai = (int*)addr;
  int old = __float_as_int(*addr);
  while (__int_as_float(old) < val) {
    int assumed = old;
    old = atomicCAS(ai, assumed, __float_as_int(val));
    if (old == assumed) break;
  }
}

// ---------------- fused weight precompute (transposed bf16 out) ----------------
// Wf_t[he][c] = sum_d Win[c][h*64+d] * rel[h][d][e];  row 512 == bias row (fp32)
__global__ void fuse_weight_kernel(const float* __restrict__ Win,
                                   const float* __restrict__ bin,
                                   const float* __restrict__ rel,
                                   unsigned short* __restrict__ Wf,
                                   float* __restrict__ bf) {
  int row = blockIdx.x;            // 0..512 (c index; 512 => bias)
  int j = threadIdx.x;             // 0..511 (h*64+e)
  int h = j >> 6, e = j & 63;
  const float* src = (row < D_) ? (Win + (long)row * D_) : bin;
  const float* rl = rel + h * 64 * 64;
  float acc = 0.f;
#pragma unroll 16
  for (int d = 0; d < 64; ++d) acc = fmaf(src[h * 64 + d], rl[d * 64 + e], acc);
  if (row < D_) Wf[(long)j * D_ + row] = f2bf(acc);
  else bf[j] = acc;
}

// ---------------- MFMA GEMM: C[MxD] = A[MxD](bf16) @ Bt^T (bf16) + bias ----------
// Bt is N-major: Bt[n][k] = W[k][n]. 128x128 tile, BK=64, 4 waves, m97 structure.
__device__ __forceinline__ void gload_lds16(const void* g, void* l) {
  __builtin_amdgcn_global_load_lds(
      (const __attribute__((address_space(1))) void*)g,
      (__attribute__((address_space(3))) void*)l, 16, 0, 0);
}

template <int OUT_BF16, int WITH_SKIP>
__global__ __launch_bounds__(256) void gemm_mfma(
    const unsigned short* __restrict__ A,
    const unsigned short* __restrict__ Bt,
    const float* __restrict__ bias,
    void* __restrict__ Cout, int M, float a_scale,
    const float* __restrict__ Hres,
    const float* __restrict__ skip, int skip_idx) {
  __shared__ unsigned short Asm[128 * 64];
  __shared__ unsigned short Bsm[128 * 64];
  const int tid = threadIdx.x;
  const int bm = blockIdx.x * 128;
  const int bn = blockIdx.y * 128;
  const int wave = tid >> 6, lane = tid & 63;
  const int wm = (wave >> 1) * 64, wn = (wave & 1) * 64;

  f32x4 acc[4][4] = {};

  const int srow = tid >> 3;        // 0..31 staging row within issue
  const int scol = (tid & 7) * 8;   // staging k offset (elems)

  for (int k0 = 0; k0 < D_; k0 += 64) {
#pragma unroll
    for (int i = 0; i < 4; ++i) {
      int gr = bm + srow + i * 32;
      if (gr >= M) gr = M - 1;  // clamp: feeds only unstored C rows
      gload_lds16(A + (long)gr * D_ + k0 + scol,
                  Asm + i * 2048 + wave * 512);
    }
#pragma unroll
    for (int i = 0; i < 4; ++i) {
      int gr = bn + srow + i * 32;  // always < 512
      gload_lds16(Bt + (long)gr * D_ + k0 + scol,
                  Bsm + i * 2048 + wave * 512);
    }
    __syncthreads();
#pragma unroll
    for (int kk = 0; kk < 2; ++kk) {
      const int ke = kk * 32 + (lane >> 4) * 8;
      const int rr = lane & 15;
      bf16x8 af[4], bfr[4];
#pragma unroll
      for (int i = 0; i < 4; ++i)
        af[i] = *(const bf16x8*)(Asm + (wm + i * 16 + rr) * 64 + ke);
#pragma unroll
      for (int j = 0; j < 4; ++j)
        bfr[j] = *(const bf16x8*)(Bsm + (wn + j * 16 + rr) * 64 + ke);
#pragma unroll
      for (int i = 0; i < 4; ++i)
#pragma unroll
        for (int j = 0; j < 4; ++j)
          acc[i][j] = __builtin_amdgcn_mfma_f32_16x16x32_bf16(
              af[i], bfr[j], acc[i][j], 0, 0, 0);
    }
    __syncthreads();
  }

  float alpha = 1.f, beta = 0.f;
  if (WITH_SKIP) {
    float sv = skip[skip_idx];
    alpha = 1.f / (1.f + expf(-sv));
    beta = 1.f - alpha;
  }
  const int cr = (lane >> 4) * 4;
  const int cc = lane & 15;
#pragma unroll
  for (int i = 0; i < 4; ++i) {
    int rowb = bm + wm + i * 16 + cr;
#pragma unroll
    for (int j = 0; j < 4; ++j) {
      int col = bn + wn + j * 16 + cc;
      float bb = bias[col];
#pragma unroll
      for (int r = 0; r < 4; ++r) {
        int row = rowb + r;
        if (row >= M) continue;
        float val = acc[i][j][r] * a_scale + bb;
        if (WITH_SKIP) val = val * alpha + Hres[(long)row * D_ + col] * beta;
        if (OUT_BF16)
          ((unsigned short*)Cout)[(long)row * D_ + col] = f2bf(val);
        else
          ((float*)Cout)[(long)row * D_ + col] = val;
      }
    }
  }
}

// ---------------- edge attention (bf16 q/k/v) ----------------
__global__ void edge_score_kernel(const unsigned short* __restrict__ q,
                                  const unsigned short* __restrict__ k,
                                  const int* __restrict__ src,
                                  const int* __restrict__ dst,
                                  const float* __restrict__ pri,
                                  float* __restrict__ s, float* __restrict__ m,
                                  int E) {
  long gid = (long)blockIdx.x * blockDim.x + threadIdx.x;
  int e = (int)(gid >> 6);
  if (e >= E) return;
  int lane = (int)(gid & 63);
  int si = src[e], di = dst[e];
  int h = lane >> 3;
  int off = (lane & 7) << 3;
  bf16x8 qv = *(const bf16x8*)(q + (long)di * D_ + h * 64 + off);
  bf16x8 kv = *(const bf16x8*)(k + (long)si * D_ + h * 64 + off);
  float acc = 0.f;
#pragma unroll
  for (int r = 0; r < 8; ++r)
    acc = fmaf(bf2f((unsigned short)qv[r]), bf2f((unsigned short)kv[r]), acc);
  acc += __shfl_xor(acc, 1);
  acc += __shfl_xor(acc, 2);
  acc += __shfl_xor(acc, 4);
  if ((lane & 7) == 0) {
    float sc = acc * pri[h] * 0.125f;  // 1/sqrt(64)
    s[(long)e * H_ + h] = sc;
    atomic_max_f(m + (long)di * H_ + h, sc);
  }
}

__global__ void edge_exp_kernel(const int* __restrict__ dst,
                                float* __restrict__ s,
                                const float* __restrict__ m,
                                float* __restrict__ den, int E) {
  long i = (long)blockIdx.x * blockDim.x + threadIdx.x;
  if (i >= (long)E * H_) return;
  int e = (int)(i >> 3), h = (int)(i & 7);
  int di = dst[e];
  float ex = expf(s[i] - m[(long)di * H_ + h]);
  s[i] = ex;
  atomic_add_f(den + (long)di * H_ + h, ex);
}

__global__ void edge_agg_kernel(const unsigned short* __restrict__ v,
                                const int* __restrict__ src,
                                const int* __restrict__ dst,
                                const float* __restrict__ ex,
                                const float* __restrict__ den,
                                float* __restrict__ agg, int E) {
  long gid = (long)blockIdx.x * blockDim.x + threadIdx.x;
  int e = (int)(gid >> 6);
  if (e >= E) return;
  int lane = (int)(gid & 63);
  int si = src[e], di = dst[e];
  const unsigned short* vr = v + (long)si * D_;
  float* ar = agg + (long)di * D_;
#pragma unroll
  for (int h = 0; h < H_; ++h) {
    float a = ex[(long)e * H_ + h] / den[(long)di * H_ + h];
    atomic_add_f(ar + h * 64 + lane, bf2f(vr[h * 64 + lane]) * a);
  }
}

// ---------------- launch ----------------
extern "C" void kernel_launch(void* const* d_in, const int* in_sizes, int n_in,
                              void* d_out, int out_size, void* d_ws, size_t ws_size,
                              hipStream_t stream) {
  const float* h_author = (const float*)d_in[0];
  const float* h_paper  = (const float*)d_in[1];
  const int* w_src = (const int*)d_in[2];
  const int* w_dst = (const int*)d_in[3];
  const int* c_src = (const int*)d_in[4];
  const int* c_dst = (const int*)d_in[5];
  const int* b_src = (const int*)d_in[6];
  const int* b_dst = (const int*)d_in[7];
  const float* Wk = (const float*)d_in[8];
  const float* bk = (const float*)d_in[9];
  const float* Wq = (const float*)d_in[10];
  const float* bq = (const float*)d_in[11];
  const float* Wv = (const float*)d_in[12];
  const float* bv = (const float*)d_in[13];
  const float* Wa = (const float*)d_in[14];
  const float* ba = (const float*)d_in[15];
  const float* rel_att = (const float*)d_in[16];
  const float* rel_msg = (const float*)d_in[17];
  const float* rel_pri = (const float*)d_in[18];
  const float* skip = (const float*)d_in[19];

  const int NA = in_sizes[0] / D_;
  const int NP = in_sizes[1] / D_;
  const int E  = in_sizes[2];
  const long nmax = (NA > NP) ? NA : NP;

  char* w = (char*)d_ws;
  unsigned short* hA16 = (unsigned short*)w; w += (long)NA * D_ * 2;
  unsigned short* hP16 = (unsigned short*)w; w += (long)NP * D_ * 2;
  unsigned short* q16  = (unsigned short*)w; w += nmax * D_ * 2;
  unsigned short* k16  = (unsigned short*)w; w += nmax * D_ * 2;
  unsigned short* v16  = (unsigned short*)w; w += nmax * D_ * 2;
  float* tbuf          = (float*)w;          w += nmax * D_ * 4;
  unsigned short* t16  = (unsigned short*)w; w += nmax * D_ * 2;
  float* sbuf          = (float*)w;          w += (long)E * H_ * 4;
  float* mbuf          = (float*)w;          w += nmax * H_ * 4;
  float* dbuf          = (float*)w;          w += nmax * H_ * 4;
  unsigned short* Wfk  = (unsigned short*)w; w += (long)D_ * D_ * 2;
  unsigned short* Wfv  = (unsigned short*)w; w += (long)D_ * D_ * 2;
  float* bfk           = (float*)w;          w += D_ * 4;
  float* bfv           = (float*)w;          w += D_ * 4;
  unsigned short* Wq0t = (unsigned short*)w; w += (long)D_ * D_ * 2;
  unsigned short* Wq1t = (unsigned short*)w; w += (long)D_ * D_ * 2;
  unsigned short* Wa0t = (unsigned short*)w; w += (long)D_ * D_ * 2;
  unsigned short* Wa1t = (unsigned short*)w; w += (long)D_ * D_ * 2;

  const long WD = (long)D_ * D_;
  const long RS = (long)H_ * 64 * 64;

  auto fill = [&](float* p, float v, long n) {
    long b = (n + 255) / 256;
    int blocks = (int)(b > 4096 ? 4096 : b);
    fill_kernel<<<blocks, 256, 0, stream>>>(p, v, n);
  };
  auto cvt = [&](const float* in, unsigned short* out, long n) {
    long n8 = n / 8;
    long b = (n8 + 255) / 256;
    int blocks = (int)(b > 2048 ? 2048 : b);
    convert_bf16_kernel<<<blocks, 256, 0, stream>>>(in, out, n8);
  };

#define GEMM16(Aa, Ww, bb, Cc, Mm)                                           \
  gemm_mfma<1, 0><<<dim3(((Mm) + 127) / 128, 4), 256, 0, stream>>>(          \
      (Aa), (Ww), (bb), (Cc), (Mm), 1.f, nullptr, nullptr, 0)
#define GEMM_SKIP(Aa, Ww, bb, Cc, Mm, sc, Hh, si)                            \
  gemm_mfma<0, 1><<<dim3(((Mm) + 127) / 128, 4), 256, 0, stream>>>(          \
      (Aa), (Ww), (bb), (Cc), (Mm), (sc), (Hh), skip, (si))

  auto run_edges = [&](const unsigned short* qb, const int* es, const int* ed,
                       const float* pri, int ndst, float* agg) {
    fill(mbuf, -INFINITY, (long)ndst * H_);
    fill(dbuf, 0.f, (long)ndst * H_);
    long th1 = (long)E * 64;
    long th2 = (long)E * H_;
    edge_score_kernel<<<(int)((th1 + 255) / 256), 256, 0, stream>>>(
        qb, k16, es, ed, pri, sbuf, mbuf, E);
    edge_exp_kernel<<<(int)((th2 + 255) / 256), 256, 0, stream>>>(
        ed, sbuf, mbuf, dbuf, E);
    edge_agg_kernel<<<(int)((th1 + 255) / 256), 256, 0, stream>>>(
        v16, es, ed, sbuf, dbuf, agg, E);
  };

  float* out_a = (float*)d_out;
  float* out_p = out_a + (long)NA * D_;

  // one-time conversions
  cvt(h_author, hA16, (long)NA * D_);
  cvt(h_paper, hP16, (long)NP * D_);
  transpose_bf16_kernel<<<D_, D_, 0, stream>>>(Wq, Wq0t);
  transpose_bf16_kernel<<<D_, D_, 0, stream>>>(Wq + WD, Wq1t);
  transpose_bf16_kernel<<<D_, D_, 0, stream>>>(Wa, Wa0t);
  transpose_bf16_kernel<<<D_, D_, 0, stream>>>(Wa + WD, Wa1t);

  // q_p = h_paper @ Wq[1] + bq[1]
  GEMM16(hP16, Wq1t, bq + D_, q16, NP);

  // ---- relation 0: writes (author -> paper) ----
  fuse_weight_kernel<<<513, 512, 0, stream>>>(Wk, bk, rel_att, Wfk, bfk);
  fuse_weight_kernel<<<513, 512, 0, stream>>>(Wv, bv, rel_msg, Wfv, bfv);
  GEMM16(hA16, Wfk, bfk, k16, NA);
  GEMM16(hA16, Wfv, bfv, v16, NA);
  fill(tbuf, 0.f, (long)NP * D_);
  run_edges(q16, w_src, w_dst, rel_pri, NP, tbuf);

  // ---- relation 1: cites (paper -> paper) ----
  fuse_weight_kernel<<<513, 512, 0, stream>>>(Wk + WD, bk + D_, rel_att + RS, Wfk, bfk);
  fuse_weight_kernel<<<513, 512, 0, stream>>>(Wv + WD, bv + D_, rel_msg + RS, Wfv, bfv);
  GEMM16(hP16, Wfk, bfk, k16, NP);
  GEMM16(hP16, Wfv, bfv, v16, NP);
  run_edges(q16, c_src, c_dst, rel_pri + H_, NP, tbuf);

  // ---- paper output ----
  cvt(tbuf, t16, (long)NP * D_);
  GEMM_SKIP(t16, Wa1t, ba + D_, out_p, NP, 0.5f, h_paper, 1);

  // q_a = h_author @ Wq[0] + bq[0]
  GEMM16(hA16, Wq0t, bq, q16, NA);

  // ---- relation 2: written_by (paper -> author) ----
  fuse_weight_kernel<<<513, 512, 0, stream>>>(Wk + WD, bk + D_, rel_att + 2 * RS, Wfk, bfk);
  fuse_weight_kernel<<<513, 512, 0, stream>>>(Wv + WD, bv + D_, rel_msg + 2 * RS, Wfv, bfv);
  GEMM16(hP16, Wfk, bfk, k16, NP);
  GEMM16(hP16, Wfv, bfv, v16, NP);
  fill(tbuf, 0.f, (long)NA * D_);
  run_edges(q16, b_src, b_dst, rel_pri + 2 * H_, NA, tbuf);

  // ---- author output ----
  cvt(tbuf, t16, (long)NA * D_);
  GEMM_SKIP(t16, Wa0t, ba, out_a, NA, 1.f, h_author, 0);

#undef GEMM16
#undef GEMM_SKIP
}

// Round 3
// 1544.158 us; speedup vs baseline: 3.3209x; 1.0431x over previous
//
#include <hip/hip_runtime.h>
#include <math.h>

#define D_ 512
#define H_ 8

typedef short bf16x8 __attribute__((ext_vector_type(8)));
typedef float f32x4 __attribute__((ext_vector_type(4)));

struct Outs { void* p[5]; };

__device__ __forceinline__ unsigned short f2bf(float x) {
  unsigned int u = __float_as_uint(x);
  unsigned int r = (u + 0x7fff + ((u >> 16) & 1)) >> 16;
  return (unsigned short)r;
}
__device__ __forceinline__ float bf2f(unsigned short b) {
  return __uint_as_float(((unsigned int)b) << 16);
}

// ---------------- utility ----------------
__global__ void fill_kernel(float* __restrict__ p, float v, long n) {
  long i = (long)blockIdx.x * blockDim.x + threadIdx.x;
  long st = (long)gridDim.x * blockDim.x;
  for (; i < n; i += st) p[i] = v;
}

__global__ void convert_bf16_kernel(const float* __restrict__ in,
                                    unsigned short* __restrict__ out, long n8) {
  long i = (long)blockIdx.x * blockDim.x + threadIdx.x;
  long st = (long)gridDim.x * blockDim.x;
  for (; i < n8; i += st) {
    float4 a = ((const float4*)in)[i * 2];
    float4 b = ((const float4*)in)[i * 2 + 1];
    bf16x8 o;
    o[0] = (short)f2bf(a.x); o[1] = (short)f2bf(a.y);
    o[2] = (short)f2bf(a.z); o[3] = (short)f2bf(a.w);
    o[4] = (short)f2bf(b.x); o[5] = (short)f2bf(b.y);
    o[6] = (short)f2bf(b.z); o[7] = (short)f2bf(b.w);
    ((bf16x8*)out)[i] = o;
  }
}

// Wt[n][k] = bf16(W[k][n]) for a 512x512 matrix
__global__ void transpose_bf16_kernel(const float* __restrict__ W,
                                      unsigned short* __restrict__ Wt) {
  int n = blockIdx.x;
  int k = threadIdx.x;
  Wt[(long)n * D_ + k] = f2bf(W[(long)k * D_ + n]);
}

__global__ void copy_bias_kernel(const float* __restrict__ in,
                                 float* __restrict__ out) {
  out[threadIdx.x] = in[threadIdx.x];
}

__device__ __forceinline__ void atomic_add_f(float* p, float v) {
  unsafeAtomicAdd(p, v);  // hardware global_atomic_add_f32
}

__device__ __forceinline__ void atomic_max_f(float* addr, float val) {
  int* ai = (int*)addr;
  int old = __float_as_int(*addr);
  while (__int_as_float(old) < val) {
    int assumed = old;
    old = atomicCAS(ai, assumed, __float_as_int(val));
    if (old == assumed) break;
  }
}

// ---------------- fused weight precompute (transposed bf16 out) ----------------
// Wf_t[he][c] = sum_d Win[c][h*64+d] * rel[h][d][e];  row 512 == bias row (fp32)
__global__ void fuse_weight_kernel(const float* __restrict__ Win,
                                   const float* __restrict__ bin,
                                   const float* __restrict__ rel,
                                   unsigned short* __restrict__ Wf,
                                   float* __restrict__ bf) {
  int row = blockIdx.x;            // 0..512 (c index; 512 => bias)
  int j = threadIdx.x;             // 0..511 (h*64+e)
  int h = j >> 6, e = j & 63;
  const float* src = (row < D_) ? (Win + (long)row * D_) : bin;
  const float* rl = rel + h * 64 * 64;
  float acc = 0.f;
#pragma unroll 16
  for (int d = 0; d < 64; ++d) acc = fmaf(src[h * 64 + d], rl[d * 64 + e], acc);
  if (row < D_) Wf[(long)j * D_ + row] = f2bf(acc);
  else bf[j] = acc;
}

// ---------------- MFMA GEMM, 2-phase double-buffered pipeline ----------------
// C[M x (GX*128)] = A[MxK=512](bf16) @ Bt^T + bias; Bt is N-major bf16.
// Output scattered to per-512-column matrices outs.p[col>>9].
__device__ __forceinline__ void gload_lds16(const void* g, void* l) {
  __builtin_amdgcn_global_load_lds(
      (const __attribute__((address_space(1))) void*)g,
      (__attribute__((address_space(3))) void*)l, 16, 0, 0);
}

template <int OUT_BF16, int WITH_SKIP>
__global__ __launch_bounds__(256) void gemm_mfma(
    const unsigned short* __restrict__ A,
    const unsigned short* __restrict__ Bt,
    const float* __restrict__ bias,
    Outs outs, int M, int GX, float a_scale,
    const float* __restrict__ Hres,
    const float* __restrict__ skip, int skip_idx) {
  __shared__ unsigned short Asm[2][128 * 64];
  __shared__ unsigned short Bsm[2][128 * 64];

  // bijective XCD-aware swizzle (m204): consecutive-in-chunk blocks share the
  // A panel; N-tile varies fastest within a chunk.
  const int nwg = gridDim.x;
  const int orig = blockIdx.x;
  const int q8 = nwg >> 3, r8 = nwg & 7;
  const int xcd = orig & 7, pos = orig >> 3;
  const int wgid =
      (xcd < r8 ? xcd * (q8 + 1) : r8 * (q8 + 1) + (xcd - r8) * q8) + pos;
  const int bm = (wgid / GX) * 128;
  const int bn = (wgid % GX) * 128;

  const int tid = threadIdx.x;
  const int wave = tid >> 6, lane = tid & 63;
  const int wm = (wave >> 1) * 64, wn = (wave & 1) * 64;
  const int srow = tid >> 3;
  const int scol = (tid & 7) * 8;

  f32x4 acc[4][4] = {};

  auto STAGE = [&](int buf, int k0) {
#pragma unroll
    for (int i = 0; i < 4; ++i) {
      int gr = bm + srow + i * 32;
      if (gr >= M) gr = M - 1;  // clamp: feeds only unstored C rows
      gload_lds16(A + (long)gr * D_ + k0 + scol,
                  &Asm[buf][i * 2048 + wave * 512]);
    }
#pragma unroll
    for (int i = 0; i < 4; ++i) {
      int gr = bn + srow + i * 32;
      gload_lds16(Bt + (long)gr * D_ + k0 + scol,
                  &Bsm[buf][i * 2048 + wave * 512]);
    }
  };

  auto COMPUTE = [&](int buf) {
#pragma unroll
    for (int kk = 0; kk < 2; ++kk) {
      const int ke = kk * 32 + (lane >> 4) * 8;
      const int rr = lane & 15;
      bf16x8 af[4], bfr[4];
#pragma unroll
      for (int i = 0; i < 4; ++i)
        af[i] = *(const bf16x8*)(&Asm[buf][(wm + i * 16 + rr) * 64 + ke]);
#pragma unroll
      for (int j = 0; j < 4; ++j)
        bfr[j] = *(const bf16x8*)(&Bsm[buf][(wn + j * 16 + rr) * 64 + ke]);
#pragma unroll
      for (int i = 0; i < 4; ++i)
#pragma unroll
        for (int j = 0; j < 4; ++j)
          acc[i][j] = __builtin_amdgcn_mfma_f32_16x16x32_bf16(
              af[i], bfr[j], acc[i][j], 0, 0, 0);
    }
  };

  // K = 512 -> 8 tiles of BK=64. Prefetch next tile before computing current.
  STAGE(0, 0);
  __syncthreads();  // emits s_waitcnt vmcnt(0) + s_barrier
#pragma unroll 1
  for (int t = 0; t < 3; ++t) {
    STAGE(1, (2 * t + 1) * 64);
    COMPUTE(0);
    __syncthreads();
    STAGE(0, (2 * t + 2) * 64);
    COMPUTE(1);
    __syncthreads();
  }
  STAGE(1, 7 * 64);
  COMPUTE(0);
  __syncthreads();
  COMPUTE(1);

  // epilogue
  float alpha = 1.f, beta = 0.f;
  if (WITH_SKIP) {
    float sv = skip[skip_idx];
    alpha = 1.f / (1.f + expf(-sv));
    beta = 1.f - alpha;
  }
  const int cr = (lane >> 4) * 4;
  const int cc = lane & 15;
  const int matu = (bn + wn) >> 9;             // wave-uniform output matrix
  const int wcb = (bn + wn) & 511;             // base col within that matrix
  unsigned short* ob16 = (unsigned short*)outs.p[matu];
  float* ob32 = (float*)outs.p[0];
#pragma unroll
  for (int i = 0; i < 4; ++i) {
    int rowb = bm + wm + i * 16 + cr;
#pragma unroll
    for (int j = 0; j < 4; ++j) {
      int col = bn + wn + j * 16 + cc;
      float bb = bias[col];
#pragma unroll
      for (int r = 0; r < 4; ++r) {
        int row = rowb + r;
        if (row >= M) continue;
        float val = acc[i][j][r] * a_scale + bb;
        if (WITH_SKIP) val = val * alpha + Hres[(long)row * D_ + col] * beta;
        if (OUT_BF16)
          ob16[(long)row * D_ + wcb + j * 16 + cc] = f2bf(val);
        else
          ob32[(long)row * D_ + col] = val;
      }
    }
  }
}

// ---------------- edge attention (bf16 q/k/v) ----------------
__global__ void edge_score_kernel(const unsigned short* __restrict__ q,
                                  const unsigned short* __restrict__ k,
                                  const int* __restrict__ src,
                                  const int* __restrict__ dst,
                                  const float* __restrict__ pri,
                                  float* __restrict__ s, float* __restrict__ m,
                                  int E) {
  long gid = (long)blockIdx.x * blockDim.x + threadIdx.x;
  int e = (int)(gid >> 6);
  if (e >= E) return;
  int lane = (int)(gid & 63);
  int si = src[e], di = dst[e];
  int h = lane >> 3;
  int off = (lane & 7) << 3;
  bf16x8 qv = *(const bf16x8*)(q + (long)di * D_ + h * 64 + off);
  bf16x8 kv = *(const bf16x8*)(k + (long)si * D_ + h * 64 + off);
  float acc = 0.f;
#pragma unroll
  for (int r = 0; r < 8; ++r)
    acc = fmaf(bf2f((unsigned short)qv[r]), bf2f((unsigned short)kv[r]), acc);
  acc += __shfl_xor(acc, 1);
  acc += __shfl_xor(acc, 2);
  acc += __shfl_xor(acc, 4);
  if ((lane & 7) == 0) {
    float sc = acc * pri[h] * 0.125f;  // 1/sqrt(64)
    s[(long)e * H_ + h] = sc;
    atomic_max_f(m + (long)di * H_ + h, sc);
  }
}

__global__ void edge_exp_kernel(const int* __restrict__ dst,
                                float* __restrict__ s,
                                const float* __restrict__ m,
                                float* __restrict__ den, int E) {
  long i = (long)blockIdx.x * blockDim.x + threadIdx.x;
  if (i >= (long)E * H_) return;
  int e = (int)(i >> 3), h = (int)(i & 7);
  int di = dst[e];
  float ex = expf(s[i] - m[(long)di * H_ + h]);
  s[i] = ex;
  atomic_add_f(den + (long)di * H_ + h, ex);
}

__global__ void edge_agg_kernel(const unsigned short* __restrict__ v,
                                const int* __restrict__ src,
                                const int* __restrict__ dst,
                                const float* __restrict__ ex,
                                const float* __restrict__ den,
                                float* __restrict__ agg, int E) {
  long gid = (long)blockIdx.x * blockDim.x + threadIdx.x;
  int e = (int)(gid >> 6);
  if (e >= E) return;
  int lane = (int)(gid & 63);
  int si = src[e], di = dst[e];
  const unsigned short* vr = v + (long)si * D_;
  float* ar = agg + (long)di * D_;
#pragma unroll
  for (int h = 0; h < H_; ++h) {
    float a = ex[(long)e * H_ + h] / den[(long)di * H_ + h];
    atomic_add_f(ar + h * 64 + lane, bf2f(vr[h * 64 + lane]) * a);
  }
}

// ---------------- launch ----------------
extern "C" void kernel_launch(void* const* d_in, const int* in_sizes, int n_in,
                              void* d_out, int out_size, void* d_ws, size_t ws_size,
                              hipStream_t stream) {
  const float* h_author = (const float*)d_in[0];
  const float* h_paper  = (const float*)d_in[1];
  const int* w_src = (const int*)d_in[2];
  const int* w_dst = (const int*)d_in[3];
  const int* c_src = (const int*)d_in[4];
  const int* c_dst = (const int*)d_in[5];
  const int* b_src = (const int*)d_in[6];
  const int* b_dst = (const int*)d_in[7];
  const float* Wk = (const float*)d_in[8];
  const float* bk = (const float*)d_in[9];
  const float* Wq = (const float*)d_in[10];
  const float* bq = (const float*)d_in[11];
  const float* Wv = (const float*)d_in[12];
  const float* bv = (const float*)d_in[13];
  const float* Wa = (const float*)d_in[14];
  const float* ba = (const float*)d_in[15];
  const float* rel_att = (const float*)d_in[16];
  const float* rel_msg = (const float*)d_in[17];
  const float* rel_pri = (const float*)d_in[18];
  const float* skip = (const float*)d_in[19];

  const int NA = in_sizes[0] / D_;
  const int NP = in_sizes[1] / D_;
  const int E  = in_sizes[2];
  const long nmax = (NA > NP) ? NA : NP;

  char* w = (char*)d_ws;
  unsigned short* hA16 = (unsigned short*)w; w += (long)NA * D_ * 2;
  unsigned short* hP16 = (unsigned short*)w; w += (long)NP * D_ * 2;
  unsigned short* Pq   = (unsigned short*)w; w += (long)NP * D_ * 2;
  unsigned short* Pkc  = (unsigned short*)w; w += (long)NP * D_ * 2;
  unsigned short* Pvc  = (unsigned short*)w; w += (long)NP * D_ * 2;
  unsigned short* Pkb  = (unsigned short*)w; w += (long)NP * D_ * 2;
  unsigned short* Pvb  = (unsigned short*)w; w += (long)NP * D_ * 2;
  unsigned short* Aq   = (unsigned short*)w; w += (long)NA * D_ * 2;
  unsigned short* Akw  = (unsigned short*)w; w += (long)NA * D_ * 2;
  unsigned short* Avw  = (unsigned short*)w; w += (long)NA * D_ * 2;
  float* tbuf          = (float*)w;          w += nmax * D_ * 4;
  unsigned short* t16  = (unsigned short*)w; w += nmax * D_ * 2;
  float* sbuf          = (float*)w;          w += (long)E * H_ * 4;
  float* mbuf          = (float*)w;          w += nmax * H_ * 4;
  float* dbuf          = (float*)w;          w += nmax * H_ * 4;
  unsigned short* BtP  = (unsigned short*)w; w += (long)2560 * D_ * 2;
  unsigned short* BtA  = (unsigned short*)w; w += (long)1536 * D_ * 2;
  float* bfP           = (float*)w;          w += 2560 * 4;
  float* bfA           = (float*)w;          w += 1536 * 4;
  unsigned short* Wa0t = (unsigned short*)w; w += (long)D_ * D_ * 2;
  unsigned short* Wa1t = (unsigned short*)w; w += (long)D_ * D_ * 2;

  const long WD = (long)D_ * D_;
  const long RS = (long)H_ * 64 * 64;
  const long SEG = (long)D_ * D_;  // 512 rows of Bt

  auto fill = [&](float* p, float v, long n) {
    long b = (n + 255) / 256;
    int blocks = (int)(b > 4096 ? 4096 : b);
    fill_kernel<<<blocks, 256, 0, stream>>>(p, v, n);
  };
  auto cvt = [&](const float* in, unsigned short* out, long n) {
    long n8 = n / 8;
    long b = (n8 + 255) / 256;
    int blocks = (int)(b > 2048 ? 2048 : b);
    convert_bf16_kernel<<<blocks, 256, 0, stream>>>(in, out, n8);
  };

  auto run_edges = [&](const unsigned short* qb, const unsigned short* kb,
                       const unsigned short* vb, const int* es, const int* ed,
                       const float* pri, int ndst, float* agg) {
    fill(mbuf, -INFINITY, (long)ndst * H_);
    fill(dbuf, 0.f, (long)ndst * H_);
    long th1 = (long)E * 64;
    long th2 = (long)E * H_;
    edge_score_kernel<<<(int)((th1 + 255) / 256), 256, 0, stream>>>(
        qb, kb, es, ed, pri, sbuf, mbuf, E);
    edge_exp_kernel<<<(int)((th2 + 255) / 256), 256, 0, stream>>>(
        ed, sbuf, mbuf, dbuf, E);
    edge_agg_kernel<<<(int)((th1 + 255) / 256), 256, 0, stream>>>(
        vb, es, ed, sbuf, dbuf, agg, E);
  };

  float* out_a = (float*)d_out;
  float* out_p = out_a + (long)NA * D_;

  // one-time conversions
  cvt(h_author, hA16, (long)NA * D_);
  cvt(h_paper, hP16, (long)NP * D_);

  // ---- build fused Bt for papers: [q_p | k_cites | v_cites | k_wb | v_wb] ----
  transpose_bf16_kernel<<<D_, D_, 0, stream>>>(Wq + WD, BtP);
  copy_bias_kernel<<<1, D_, 0, stream>>>(bq + D_, bfP);
  fuse_weight_kernel<<<513, 512, 0, stream>>>(Wk + WD, bk + D_, rel_att + RS,
                                              BtP + SEG, bfP + 512);
  fuse_weight_kernel<<<513, 512, 0, stream>>>(Wv + WD, bv + D_, rel_msg + RS,
                                              BtP + 2 * SEG, bfP + 1024);
  fuse_weight_kernel<<<513, 512, 0, stream>>>(Wk + WD, bk + D_, rel_att + 2 * RS,
                                              BtP + 3 * SEG, bfP + 1536);
  fuse_weight_kernel<<<513, 512, 0, stream>>>(Wv + WD, bv + D_, rel_msg + 2 * RS,
                                              BtP + 4 * SEG, bfP + 2048);

  // ---- fused Bt for authors: [q_a | k_writes | v_writes] ----
  transpose_bf16_kernel<<<D_, D_, 0, stream>>>(Wq, BtA);
  copy_bias_kernel<<<1, D_, 0, stream>>>(bq, bfA);
  fuse_weight_kernel<<<513, 512, 0, stream>>>(Wk, bk, rel_att,
                                              BtA + SEG, bfA + 512);
  fuse_weight_kernel<<<513, 512, 0, stream>>>(Wv, bv, rel_msg,
                                              BtA + 2 * SEG, bfA + 1024);

  // output-projection weights
  transpose_bf16_kernel<<<D_, D_, 0, stream>>>(Wa, Wa0t);
  transpose_bf16_kernel<<<D_, D_, 0, stream>>>(Wa + WD, Wa1t);

  // ---- fused projection GEMMs ----
  {
    Outs o; o.p[0] = Pq; o.p[1] = Pkc; o.p[2] = Pvc; o.p[3] = Pkb; o.p[4] = Pvb;
    int gy = (NP + 127) / 128;
    gemm_mfma<1, 0><<<20 * gy, 256, 0, stream>>>(
        hP16, BtP, bfP, o, NP, 20, 1.f, nullptr, nullptr, 0);
  }
  {
    Outs o; o.p[0] = Aq; o.p[1] = Akw; o.p[2] = Avw; o.p[3] = Aq; o.p[4] = Aq;
    int gy = (NA + 127) / 128;
    gemm_mfma<1, 0><<<12 * gy, 256, 0, stream>>>(
        hA16, BtA, bfA, o, NA, 12, 1.f, nullptr, nullptr, 0);
  }

  // ---- edge attention: rel0 writes (author->paper), rel1 cites (paper->paper) ----
  fill(tbuf, 0.f, (long)NP * D_);
  run_edges(Pq, Akw, Avw, w_src, w_dst, rel_pri, NP, tbuf);
  run_edges(Pq, Pkc, Pvc, c_src, c_dst, rel_pri + H_, NP, tbuf);

  // ---- paper output ----
  cvt(tbuf, t16, (long)NP * D_);
  {
    Outs o; o.p[0] = out_p; o.p[1] = o.p[2] = o.p[3] = o.p[4] = out_p;
    int gy = (NP + 127) / 128;
    gemm_mfma<0, 1><<<4 * gy, 256, 0, stream>>>(
        t16, Wa1t, ba + D_, o, NP, 4, 0.5f, h_paper, skip, 1);
  }

  // ---- rel2 written_by (paper->author) ----
  fill(tbuf, 0.f, (long)NA * D_);
  run_edges(Aq, Pkb, Pvb, b_src, b_dst, rel_pri + 2 * H_, NA, tbuf);

  // ---- author output ----
  cvt(tbuf, t16, (long)NA * D_);
  {
    Outs o; o.p[0] = out_a; o.p[1] = o.p[2] = o.p[3] = o.p[4] = out_a;
    int gy = (NA + 127) / 128;
    gemm_mfma<0, 1><<<4 * gy, 256, 0, stream>>>(
        t16, Wa0t, ba, o, NA, 4, 1.f, h_author, skip, 0);
  }
}

// Round 4
// 1518.983 us; speedup vs baseline: 3.3759x; 1.0166x over previous
//
#include <hip/hip_runtime.h>
#include <math.h>

#define D_ 512
#define H_ 8

typedef short bf16x8 __attribute__((ext_vector_type(8)));
typedef float f32x4 __attribute__((ext_vector_type(4)));

struct Outs { void* p[5]; };

__device__ __forceinline__ unsigned short f2bf(float x) {
  unsigned int u = __float_as_uint(x);
  unsigned int r = (u + 0x7fff + ((u >> 16) & 1)) >> 16;
  return (unsigned short)r;
}
__device__ __forceinline__ float bf2f(unsigned short b) {
  return __uint_as_float(((unsigned int)b) << 16);
}

// ---------------- utility ----------------
__global__ void fill_kernel(float* __restrict__ p, float v, long n) {
  long i = (long)blockIdx.x * blockDim.x + threadIdx.x;
  long st = (long)gridDim.x * blockDim.x;
  for (; i < n; i += st) p[i] = v;
}

__global__ void convert_bf16_kernel(const float* __restrict__ in,
                                    unsigned short* __restrict__ out, long n8) {
  long i = (long)blockIdx.x * blockDim.x + threadIdx.x;
  long st = (long)gridDim.x * blockDim.x;
  for (; i < n8; i += st) {
    float4 a = ((const float4*)in)[i * 2];
    float4 b = ((const float4*)in)[i * 2 + 1];
    bf16x8 o;
    o[0] = (short)f2bf(a.x); o[1] = (short)f2bf(a.y);
    o[2] = (short)f2bf(a.z); o[3] = (short)f2bf(a.w);
    o[4] = (short)f2bf(b.x); o[5] = (short)f2bf(b.y);
    o[6] = (short)f2bf(b.z); o[7] = (short)f2bf(b.w);
    ((bf16x8*)out)[i] = o;
  }
}

// Wt[n][k] = bf16(W[k][n]) for a 512x512 matrix
__global__ void transpose_bf16_kernel(const float* __restrict__ W,
                                      unsigned short* __restrict__ Wt) {
  int n = blockIdx.x;
  int k = threadIdx.x;
  Wt[(long)n * D_ + k] = f2bf(W[(long)k * D_ + n]);
}

__global__ void copy_bias_kernel(const float* __restrict__ in,
                                 float* __restrict__ out) {
  out[threadIdx.x] = in[threadIdx.x];
}

__device__ __forceinline__ void atomic_add_f(float* p, float v) {
  unsafeAtomicAdd(p, v);  // hardware global_atomic_add_f32
}

__device__ __forceinline__ void atomic_max_f(float* addr, float val) {
  int* ai = (int*)addr;
  int old = __float_as_int(*addr);
  while (__int_as_float(old) < val) {
    int assumed = old;
    old = atomicCAS(ai, assumed, __float_as_int(val));
    if (old == assumed) break;
  }
}

// ---------------- fused weight precompute (transposed bf16 out) ----------------
__global__ void fuse_weight_kernel(const float* __restrict__ Win,
                                   const float* __restrict__ bin,
                                   const float* __restrict__ rel,
                                   unsigned short* __restrict__ Wf,
                                   float* __restrict__ bf) {
  int row = blockIdx.x;            // 0..512 (c index; 512 => bias)
  int j = threadIdx.x;             // 0..511 (h*64+e)
  int h = j >> 6, e = j & 63;
  const float* src = (row < D_) ? (Win + (long)row * D_) : bin;
  const float* rl = rel + h * 64 * 64;
  float acc = 0.f;
#pragma unroll 16
  for (int d = 0; d < 64; ++d) acc = fmaf(src[h * 64 + d], rl[d * 64 + e], acc);
  if (row < D_) Wf[(long)j * D_ + row] = f2bf(acc);
  else bf[j] = acc;
}

// ---------------- MFMA GEMM: single-buffer m97 loop + T2 XOR swizzle ---------
// C[M x (GX*128)] = A[MxK=512](bf16) @ Bt^T + bias; Bt is N-major bf16.
// LDS kept LINEAR (global_load_lds writes base+lane*16); the swizzle is applied
// by permuting the per-lane GLOBAL source column and the matching XOR on the
// ds_read byte address (rule #21: both-sides-or-neither).
__device__ __forceinline__ void gload_lds16(const void* g, void* l) {
  __builtin_amdgcn_global_load_lds(
      (const __attribute__((address_space(1))) void*)g,
      (__attribute__((address_space(3))) void*)l, 16, 0, 0);
}

template <int OUT_BF16, int WITH_SKIP>
__global__ __launch_bounds__(256) void gemm_mfma(
    const unsigned short* __restrict__ A,
    const unsigned short* __restrict__ Bt,
    const float* __restrict__ bias,
    Outs outs, int M, int GX, float a_scale,
    const float* __restrict__ Hres,
    const float* __restrict__ skip, int skip_idx) {
  __shared__ unsigned short Asm[128 * 64];
  __shared__ unsigned short Bsm[128 * 64];

  // bijective XCD-aware swizzle (m204); N-tile fastest within a chunk.
  const int nwg = gridDim.x;
  const int orig = blockIdx.x;
  const int q8 = nwg >> 3, r8 = nwg & 7;
  const int xcd = orig & 7, pos = orig >> 3;
  const int wgid =
      (xcd < r8 ? xcd * (q8 + 1) : r8 * (q8 + 1) + (xcd - r8) * q8) + pos;
  const int bm = (wgid / GX) * 128;
  const int bn = (wgid % GX) * 128;

  const int tid = threadIdx.x;
  const int wave = tid >> 6, lane = tid & 63;
  const int wm = (wave >> 1) * 64, wn = (wave & 1) * 64;
  const int srow = tid >> 3;                         // staging row 0..31
  const int swz = ((tid & 7) ^ (srow & 7)) * 8;      // pre-swizzled src col (elems)

  f32x4 acc[4][4] = {};

  const int rr = lane & 15;
  const int rx = (rr & 7) << 4;                      // read-side XOR (bytes)

  for (int k0 = 0; k0 < D_; k0 += 64) {
#pragma unroll
    for (int i = 0; i < 4; ++i) {
      int gr = bm + srow + i * 32;
      if (gr >= M) gr = M - 1;  // clamp: feeds only unstored C rows
      gload_lds16(A + (long)gr * D_ + k0 + swz, Asm + i * 2048 + wave * 512);
    }
#pragma unroll
    for (int i = 0; i < 4; ++i) {
      int gr = bn + srow + i * 32;
      gload_lds16(Bt + (long)gr * D_ + k0 + swz, Bsm + i * 2048 + wave * 512);
    }
    __syncthreads();
#pragma unroll
    for (int kk = 0; kk < 2; ++kk) {
      const int cb = kk * 64 + (lane >> 4) * 16;     // logical byte col
      const int cs = cb ^ rx;                        // swizzled byte col
      bf16x8 af[4], bfr[4];
#pragma unroll
      for (int i = 0; i < 4; ++i)
        af[i] = *(const bf16x8*)((const char*)Asm + (wm + i * 16 + rr) * 128 + cs);
#pragma unroll
      for (int j = 0; j < 4; ++j)
        bfr[j] = *(const bf16x8*)((const char*)Bsm + (wn + j * 16 + rr) * 128 + cs);
#pragma unroll
      for (int i = 0; i < 4; ++i)
#pragma unroll
        for (int j = 0; j < 4; ++j)
          acc[i][j] = __builtin_amdgcn_mfma_f32_16x16x32_bf16(
              af[i], bfr[j], acc[i][j], 0, 0, 0);
    }
    __syncthreads();
  }

  // epilogue
  float alpha = 1.f, beta = 0.f;
  if (WITH_SKIP) {
    float sv = skip[skip_idx];
    alpha = 1.f / (1.f + expf(-sv));
    beta = 1.f - alpha;
  }
  const int cr = (lane >> 4) * 4;
  const int cc = lane & 15;
  const int matu = (bn + wn) >> 9;             // wave-uniform output matrix
  const int wcb = (bn + wn) & 511;             // base col within that matrix
  unsigned short* ob16 = (unsigned short*)outs.p[matu];
  float* ob32 = (float*)outs.p[0];
#pragma unroll
  for (int i = 0; i < 4; ++i) {
    int rowb = bm + wm + i * 16 + cr;
#pragma unroll
    for (int j = 0; j < 4; ++j) {
      int col = bn + wn + j * 16 + cc;
      float bb = bias[col];
#pragma unroll
      for (int r = 0; r < 4; ++r) {
        int row = rowb + r;
        if (row >= M) continue;
        float val = acc[i][j][r] * a_scale + bb;
        if (WITH_SKIP) val = val * alpha + Hres[(long)row * D_ + col] * beta;
        if (OUT_BF16)
          ob16[(long)row * D_ + wcb + j * 16 + cc] = f2bf(val);
        else
          ob32[(long)row * D_ + col] = val;
      }
    }
  }
}

// ---------------- edge attention (bf16 q/k/v) ----------------
__global__ void edge_score_kernel(const unsigned short* __restrict__ q,
                                  const unsigned short* __restrict__ k,
                                  const int* __restrict__ src,
                                  const int* __restrict__ dst,
                                  const float* __restrict__ pri,
                                  float* __restrict__ s, float* __restrict__ m,
                                  int E) {
  long gid = (long)blockIdx.x * blockDim.x + threadIdx.x;
  int e = (int)(gid >> 6);
  if (e >= E) return;
  int lane = (int)(gid & 63);
  int si = src[e], di = dst[e];
  int h = lane >> 3;
  int off = (lane & 7) << 3;
  bf16x8 qv = *(const bf16x8*)(q + (long)di * D_ + h * 64 + off);
  bf16x8 kv = *(const bf16x8*)(k + (long)si * D_ + h * 64 + off);
  float acc = 0.f;
#pragma unroll
  for (int r = 0; r < 8; ++r)
    acc = fmaf(bf2f((unsigned short)qv[r]), bf2f((unsigned short)kv[r]), acc);
  acc += __shfl_xor(acc, 1);
  acc += __shfl_xor(acc, 2);
  acc += __shfl_xor(acc, 4);
  if ((lane & 7) == 0) {
    float sc = acc * pri[h] * 0.125f;  // 1/sqrt(64)
    s[(long)e * H_ + h] = sc;
    atomic_max_f(m + (long)di * H_ + h, sc);
  }
}

__global__ void edge_exp_kernel(const int* __restrict__ dst,
                                float* __restrict__ s,
                                const float* __restrict__ m,
                                float* __restrict__ den, int E) {
  long i = (long)blockIdx.x * blockDim.x + threadIdx.x;
  if (i >= (long)E * H_) return;
  int e = (int)(i >> 3), h = (int)(i & 7);
  int di = dst[e];
  float ex = expf(s[i] - m[(long)di * H_ + h]);
  s[i] = ex;
  atomic_add_f(den + (long)di * H_ + h, ex);
}

__global__ void edge_agg_kernel(const unsigned short* __restrict__ v,
                                const int* __restrict__ src,
                                const int* __restrict__ dst,
                                const float* __restrict__ ex,
                                const float* __restrict__ den,
                                float* __restrict__ agg, int E) {
  long gid = (long)blockIdx.x * blockDim.x + threadIdx.x;
  int e = (int)(gid >> 6);
  if (e >= E) return;
  int lane = (int)(gid & 63);
  int si = src[e], di = dst[e];
  const unsigned short* vr = v + (long)si * D_;
  float* ar = agg + (long)di * D_;
#pragma unroll
  for (int h = 0; h < H_; ++h) {
    float a = ex[(long)e * H_ + h] / den[(long)di * H_ + h];
    atomic_add_f(ar + h * 64 + lane, bf2f(vr[h * 64 + lane]) * a);
  }
}

// ---------------- launch ----------------
extern "C" void kernel_launch(void* const* d_in, const int* in_sizes, int n_in,
                              void* d_out, int out_size, void* d_ws, size_t ws_size,
                              hipStream_t stream) {
  const float* h_author = (const float*)d_in[0];
  const float* h_paper  = (const float*)d_in[1];
  const int* w_src = (const int*)d_in[2];
  const int* w_dst = (const int*)d_in[3];
  const int* c_src = (const int*)d_in[4];
  const int* c_dst = (const int*)d_in[5];
  const int* b_src = (const int*)d_in[6];
  const int* b_dst = (const int*)d_in[7];
  const float* Wk = (const float*)d_in[8];
  const float* bk = (const float*)d_in[9];
  const float* Wq = (const float*)d_in[10];
  const float* bq = (const float*)d_in[11];
  const float* Wv = (const float*)d_in[12];
  const float* bv = (const float*)d_in[13];
  const float* Wa = (const float*)d_in[14];
  const float* ba = (const float*)d_in[15];
  const float* rel_att = (const float*)d_in[16];
  const float* rel_msg = (const float*)d_in[17];
  const float* rel_pri = (const float*)d_in[18];
  const float* skip = (const float*)d_in[19];

  const int NA = in_sizes[0] / D_;
  const int NP = in_sizes[1] / D_;
  const int E  = in_sizes[2];
  const long nmax = (NA > NP) ? NA : NP;

  char* w = (char*)d_ws;
  unsigned short* hA16 = (unsigned short*)w; w += (long)NA * D_ * 2;
  unsigned short* hP16 = (unsigned short*)w; w += (long)NP * D_ * 2;
  unsigned short* Pq   = (unsigned short*)w; w += (long)NP * D_ * 2;
  unsigned short* Pkc  = (unsigned short*)w; w += (long)NP * D_ * 2;
  unsigned short* Pvc  = (unsigned short*)w; w += (long)NP * D_ * 2;
  unsigned short* Pkb  = (unsigned short*)w; w += (long)NP * D_ * 2;
  unsigned short* Pvb  = (unsigned short*)w; w += (long)NP * D_ * 2;
  unsigned short* Aq   = (unsigned short*)w; w += (long)NA * D_ * 2;
  unsigned short* Akw  = (unsigned short*)w; w += (long)NA * D_ * 2;
  unsigned short* Avw  = (unsigned short*)w; w += (long)NA * D_ * 2;
  float* tbuf          = (float*)w;          w += nmax * D_ * 4;
  unsigned short* t16  = (unsigned short*)w; w += nmax * D_ * 2;
  float* sbuf          = (float*)w;          w += (long)E * H_ * 4;
  float* mbuf          = (float*)w;          w += nmax * H_ * 4;
  float* dbuf          = (float*)w;          w += nmax * H_ * 4;
  unsigned short* BtP  = (unsigned short*)w; w += (long)2560 * D_ * 2;
  unsigned short* BtA  = (unsigned short*)w; w += (long)1536 * D_ * 2;
  float* bfP           = (float*)w;          w += 2560 * 4;
  float* bfA           = (float*)w;          w += 1536 * 4;
  unsigned short* Wa0t = (unsigned short*)w; w += (long)D_ * D_ * 2;
  unsigned short* Wa1t = (unsigned short*)w; w += (long)D_ * D_ * 2;

  const long WD = (long)D_ * D_;
  const long RS = (long)H_ * 64 * 64;
  const long SEG = (long)D_ * D_;  // 512 rows of Bt

  auto fill = [&](float* p, float v, long n) {
    long b = (n + 255) / 256;
    int blocks = (int)(b > 4096 ? 4096 : b);
    fill_kernel<<<blocks, 256, 0, stream>>>(p, v, n);
  };
  auto cvt = [&](const float* in, unsigned short* out, long n) {
    long n8 = n / 8;
    long b = (n8 + 255) / 256;
    int blocks = (int)(b > 2048 ? 2048 : b);
    convert_bf16_kernel<<<blocks, 256, 0, stream>>>(in, out, n8);
  };

  auto run_edges = [&](const unsigned short* qb, const unsigned short* kb,
                       const unsigned short* vb, const int* es, const int* ed,
                       const float* pri, int ndst, float* agg) {
    fill(mbuf, -INFINITY, (long)ndst * H_);
    fill(dbuf, 0.f, (long)ndst * H_);
    long th1 = (long)E * 64;
    long th2 = (long)E * H_;
    edge_score_kernel<<<(int)((th1 + 255) / 256), 256, 0, stream>>>(
        qb, kb, es, ed, pri, sbuf, mbuf, E);
    edge_exp_kernel<<<(int)((th2 + 255) / 256), 256, 0, stream>>>(
        ed, sbuf, mbuf, dbuf, E);
    edge_agg_kernel<<<(int)((th1 + 255) / 256), 256, 0, stream>>>(
        vb, es, ed, sbuf, dbuf, agg, E);
  };

  float* out_a = (float*)d_out;
  float* out_p = out_a + (long)NA * D_;

  // one-time conversions
  cvt(h_author, hA16, (long)NA * D_);
  cvt(h_paper, hP16, (long)NP * D_);

  // ---- build fused Bt for papers: [q_p | k_cites | v_cites | k_wb | v_wb] ----
  transpose_bf16_kernel<<<D_, D_, 0, stream>>>(Wq + WD, BtP);
  copy_bias_kernel<<<1, D_, 0, stream>>>(bq + D_, bfP);
  fuse_weight_kernel<<<513, 512, 0, stream>>>(Wk + WD, bk + D_, rel_att + RS,
                                              BtP + SEG, bfP + 512);
  fuse_weight_kernel<<<513, 512, 0, stream>>>(Wv + WD, bv + D_, rel_msg + RS,
                                              BtP + 2 * SEG, bfP + 1024);
  fuse_weight_kernel<<<513, 512, 0, stream>>>(Wk + WD, bk + D_, rel_att + 2 * RS,
                                              BtP + 3 * SEG, bfP + 1536);
  fuse_weight_kernel<<<513, 512, 0, stream>>>(Wv + WD, bv + D_, rel_msg + 2 * RS,
                                              BtP + 4 * SEG, bfP + 2048);

  // ---- fused Bt for authors: [q_a | k_writes | v_writes] ----
  transpose_bf16_kernel<<<D_, D_, 0, stream>>>(Wq, BtA);
  copy_bias_kernel<<<1, D_, 0, stream>>>(bq, bfA);
  fuse_weight_kernel<<<513, 512, 0, stream>>>(Wk, bk, rel_att,
                                              BtA + SEG, bfA + 512);
  fuse_weight_kernel<<<513, 512, 0, stream>>>(Wv, bv, rel_msg,
                                              BtA + 2 * SEG, bfA + 1024);

  // output-projection weights
  transpose_bf16_kernel<<<D_, D_, 0, stream>>>(Wa, Wa0t);
  transpose_bf16_kernel<<<D_, D_, 0, stream>>>(Wa + WD, Wa1t);

  // ---- fused projection GEMMs ----
  {
    Outs o; o.p[0] = Pq; o.p[1] = Pkc; o.p[2] = Pvc; o.p[3] = Pkb; o.p[4] = Pvb;
    int gy = (NP + 127) / 128;
    gemm_mfma<1, 0><<<20 * gy, 256, 0, stream>>>(
        hP16, BtP, bfP, o, NP, 20, 1.f, nullptr, nullptr, 0);
  }
  {
    Outs o; o.p[0] = Aq; o.p[1] = Akw; o.p[2] = Avw; o.p[3] = Aq; o.p[4] = Aq;
    int gy = (NA + 127) / 128;
    gemm_mfma<1, 0><<<12 * gy, 256, 0, stream>>>(
        hA16, BtA, bfA, o, NA, 12, 1.f, nullptr, nullptr, 0);
  }

  // ---- edge attention: rel0 writes (author->paper), rel1 cites (paper->paper) ----
  fill(tbuf, 0.f, (long)NP * D_);
  run_edges(Pq, Akw, Avw, w_src, w_dst, rel_pri, NP, tbuf);
  run_edges(Pq, Pkc, Pvc, c_src, c_dst, rel_pri + H_, NP, tbuf);

  // ---- paper output ----
  cvt(tbuf, t16, (long)NP * D_);
  {
    Outs o; o.p[0] = out_p; o.p[1] = o.p[2] = o.p[3] = o.p[4] = out_p;
    int gy = (NP + 127) / 128;
    gemm_mfma<0, 1><<<4 * gy, 256, 0, stream>>>(
        t16, Wa1t, ba + D_, o, NP, 4, 0.5f, h_paper, skip, 1);
  }

  // ---- rel2 written_by (paper->author) ----
  fill(tbuf, 0.f, (long)NA * D_);
  run_edges(Aq, Pkb, Pvb, b_src, b_dst, rel_pri + 2 * H_, NA, tbuf);

  // ---- author output ----
  cvt(tbuf, t16, (long)NA * D_);
  {
    Outs o; o.p[0] = out_a; o.p[1] = o.p[2] = o.p[3] = o.p[4] = out_a;
    int gy = (NA + 127) / 128;
    gemm_mfma<0, 1><<<4 * gy, 256, 0, stream>>>(
        t16, Wa0t, ba, o, NA, 4, 1.f, h_author, skip, 0);
  }
}

// Round 5
// 1063.888 us; speedup vs baseline: 4.8200x; 1.4278x over previous
//
#include <hip/hip_runtime.h>
#include <math.h>

#define D_ 512
#define H_ 8

typedef short bf16x8 __attribute__((ext_vector_type(8)));
typedef float f32x4 __attribute__((ext_vector_type(4)));

struct Outs { void* p[5]; };

__device__ __forceinline__ unsigned short f2bf(float x) {
  unsigned int u = __float_as_uint(x);
  unsigned int r = (u + 0x7fff + ((u >> 16) & 1)) >> 16;
  return (unsigned short)r;
}
__device__ __forceinline__ float bf2f(unsigned short b) {
  return __uint_as_float(((unsigned int)b) << 16);
}

// ---------------- utility ----------------
__global__ void fill_kernel(float* __restrict__ p, float v, long n) {
  long i = (long)blockIdx.x * blockDim.x + threadIdx.x;
  long st = (long)gridDim.x * blockDim.x;
  for (; i < n; i += st) p[i] = v;
}

__global__ void convert_bf16_kernel(const float* __restrict__ in,
                                    unsigned short* __restrict__ out, long n8) {
  long i = (long)blockIdx.x * blockDim.x + threadIdx.x;
  long st = (long)gridDim.x * blockDim.x;
  for (; i < n8; i += st) {
    float4 a = ((const float4*)in)[i * 2];
    float4 b = ((const float4*)in)[i * 2 + 1];
    bf16x8 o;
    o[0] = (short)f2bf(a.x); o[1] = (short)f2bf(a.y);
    o[2] = (short)f2bf(a.z); o[3] = (short)f2bf(a.w);
    o[4] = (short)f2bf(b.x); o[5] = (short)f2bf(b.y);
    o[6] = (short)f2bf(b.z); o[7] = (short)f2bf(b.w);
    ((bf16x8*)out)[i] = o;
  }
}

// Wt[n][k] = bf16(W[k][n]) for a 512x512 matrix
__global__ void transpose_bf16_kernel(const float* __restrict__ W,
                                      unsigned short* __restrict__ Wt) {
  int n = blockIdx.x;
  int k = threadIdx.x;
  Wt[(long)n * D_ + k] = f2bf(W[(long)k * D_ + n]);
}

__global__ void copy_bias_kernel(const float* __restrict__ in,
                                 float* __restrict__ out) {
  out[threadIdx.x] = in[threadIdx.x];
}

// ---------------- fused weight precompute (transposed bf16 out) ----------------
__global__ void fuse_weight_kernel(const float* __restrict__ Win,
                                   const float* __restrict__ bin,
                                   const float* __restrict__ rel,
                                   unsigned short* __restrict__ Wf,
                                   float* __restrict__ bf) {
  int row = blockIdx.x;            // 0..512 (c index; 512 => bias)
  int j = threadIdx.x;             // 0..511 (h*64+e)
  int h = j >> 6, e = j & 63;
  const float* src = (row < D_) ? (Win + (long)row * D_) : bin;
  const float* rl = rel + h * 64 * 64;
  float acc = 0.f;
#pragma unroll 16
  for (int d = 0; d < 64; ++d) acc = fmaf(src[h * 64 + d], rl[d * 64 + e], acc);
  if (row < D_) Wf[(long)j * D_ + row] = f2bf(acc);
  else bf[j] = acc;
}

// ---------------- CSR build: hist -> scan -> scatter ----------------
__global__ void hist_kernel(const int* __restrict__ w_dst,
                            const int* __restrict__ c_dst,
                            const int* __restrict__ b_dst,
                            int* __restrict__ degree, int E, int NP) {
  int i = blockIdx.x * blockDim.x + threadIdx.x;
  if (i >= 3 * E) return;
  int r = i / E, e = i - r * E;
  int d, base;
  if (r == 0)      { d = w_dst[e]; base = 0; }
  else if (r == 1) { d = c_dst[e]; base = NP; }
  else             { d = b_dst[e]; base = 2 * NP; }
  atomicAdd(degree + base + d, 1);
}

__global__ void scan1_kernel(const int* __restrict__ in, int* __restrict__ out,
                             int* __restrict__ aux, int n) {
  __shared__ int tmp[256];
  int t = threadIdx.x;
  int i = blockIdx.x * 256 + t;
  int v = (i < n) ? in[i] : 0;
  tmp[t] = v;
  __syncthreads();
#pragma unroll
  for (int d = 1; d < 256; d <<= 1) {
    int add = (t >= d) ? tmp[t - d] : 0;
    __syncthreads();
    tmp[t] += add;
    __syncthreads();
  }
  if (i < n) out[i] = tmp[t] - v;   // exclusive
  if (t == 255) aux[blockIdx.x] = tmp[255];
}

__global__ void scan2_kernel(int* __restrict__ aux, int nb) {
  __shared__ int tmp[1024];
  int t = threadIdx.x;
  int v = (t < nb) ? aux[t] : 0;
  tmp[t] = v;
  __syncthreads();
#pragma unroll
  for (int d = 1; d < 1024; d <<= 1) {
    int add = (t >= d) ? tmp[t - d] : 0;
    __syncthreads();
    tmp[t] += add;
    __syncthreads();
  }
  if (t < nb) aux[t] = tmp[t] - v;  // exclusive block offsets
}

__global__ void scan3_kernel(int* __restrict__ starts, int* __restrict__ cursor,
                             const int* __restrict__ aux, int n) {
  int i = blockIdx.x * 256 + threadIdx.x;
  if (i >= n) return;
  int s = starts[i] + aux[blockIdx.x];
  starts[i] = s;
  cursor[i] = s;
}

__global__ void scatter_kernel(const int* __restrict__ w_src, const int* __restrict__ w_dst,
                               const int* __restrict__ c_src, const int* __restrict__ c_dst,
                               const int* __restrict__ b_src, const int* __restrict__ b_dst,
                               int* __restrict__ cursor, int* __restrict__ csr,
                               int E, int NP) {
  int i = blockIdx.x * blockDim.x + threadIdx.x;
  if (i >= 3 * E) return;
  int r = i / E, e = i - r * E;
  int s, d, base;
  if (r == 0)      { s = w_src[e]; d = w_dst[e]; base = 0; }
  else if (r == 1) { s = c_src[e]; d = c_dst[e]; base = NP; }
  else             { s = b_src[e]; d = b_dst[e]; base = 2 * NP; }
  int pos = atomicAdd(cursor + base + d, 1);
  csr[pos] = s;
}

// ---------------- fused per-node edge attention (flash-style) ----------------
// One 64-lane wave per dst node; lane l -> head h=l>>3, 8 elems at (l&7)*8.
// TWO_LISTS: papers consume writes-list (k0/v0) and cites-list (k1/v1), each
// with an independent online softmax; result = outscale * sum of per-list agg.
template <int TWO_LISTS>
__global__ __launch_bounds__(256) void attn_kernel(
    const unsigned short* __restrict__ q,
    const unsigned short* __restrict__ k0, const unsigned short* __restrict__ v0,
    const unsigned short* __restrict__ k1, const unsigned short* __restrict__ v1,
    const int* __restrict__ csr, const int* __restrict__ starts,
    const int* __restrict__ degree, int base0, int base1,
    const float* __restrict__ pri, int poff0, int poff1,
    unsigned short* __restrict__ out, int n_nodes, float outscale) {
  int gw = (int)(((long)blockIdx.x * blockDim.x + threadIdx.x) >> 6);
  if (gw >= n_nodes) return;
  int lane = threadIdx.x & 63;
  int h = lane >> 3, off = (lane & 7) << 3;
  const long rowoff = (long)gw * D_ + h * 64 + off;
  bf16x8 qv = *(const bf16x8*)(q + rowoff);
  float qf[8];
#pragma unroll
  for (int r = 0; r < 8; ++r) qf[r] = bf2f((unsigned short)qv[r]);

  float res[8] = {};

  auto process = [&](const unsigned short* K, const unsigned short* V,
                     int base, float ps) {
    int st = starts[base + gw], dg = degree[base + gw];
    float m = -INFINITY, l = 0.f;
    float acc[8] = {};
    for (int i = 0; i < dg; ++i) {
      int s = csr[st + i];
      const long ro = (long)s * D_ + h * 64 + off;
      bf16x8 kv = *(const bf16x8*)(K + ro);
      bf16x8 vv = *(const bf16x8*)(V + ro);
      float dot = 0.f;
#pragma unroll
      for (int r = 0; r < 8; ++r)
        dot = fmaf(qf[r], bf2f((unsigned short)kv[r]), dot);
      dot += __shfl_xor(dot, 1);
      dot += __shfl_xor(dot, 2);
      dot += __shfl_xor(dot, 4);
      float sc = dot * ps;
      float mn = fmaxf(m, sc);
      float scale = __expf(m - mn);   // m=-inf first edge -> 0
      float p = __expf(sc - mn);
      l = l * scale + p;
#pragma unroll
      for (int r = 0; r < 8; ++r)
        acc[r] = acc[r] * scale + p * bf2f((unsigned short)vv[r]);
      m = mn;
    }
    if (l > 0.f) {
      float inv = 1.f / l;
#pragma unroll
      for (int r = 0; r < 8; ++r) res[r] += acc[r] * inv;
    }
  };

  process(k0, v0, base0, pri[poff0 + h] * 0.125f);
  if (TWO_LISTS) process(k1, v1, base1, pri[poff1 + h] * 0.125f);

  bf16x8 o;
#pragma unroll
  for (int r = 0; r < 8; ++r) o[r] = (short)f2bf(res[r] * outscale);
  *(bf16x8*)(out + rowoff) = o;
}

// ---------------- MFMA GEMM: single-buffer m97 loop + T2 XOR swizzle ---------
__device__ __forceinline__ void gload_lds16(const void* g, void* l) {
  __builtin_amdgcn_global_load_lds(
      (const __attribute__((address_space(1))) void*)g,
      (__attribute__((address_space(3))) void*)l, 16, 0, 0);
}

template <int OUT_BF16, int WITH_SKIP>
__global__ __launch_bounds__(256) void gemm_mfma(
    const unsigned short* __restrict__ A,
    const unsigned short* __restrict__ Bt,
    const float* __restrict__ bias,
    Outs outs, int M, int GX, float a_scale,
    const float* __restrict__ Hres,
    const float* __restrict__ skip, int skip_idx) {
  __shared__ unsigned short Asm[128 * 64];
  __shared__ unsigned short Bsm[128 * 64];

  const int nwg = gridDim.x;
  const int orig = blockIdx.x;
  const int q8 = nwg >> 3, r8 = nwg & 7;
  const int xcd = orig & 7, pos = orig >> 3;
  const int wgid =
      (xcd < r8 ? xcd * (q8 + 1) : r8 * (q8 + 1) + (xcd - r8) * q8) + pos;
  const int bm = (wgid / GX) * 128;
  const int bn = (wgid % GX) * 128;

  const int tid = threadIdx.x;
  const int wave = tid >> 6, lane = tid & 63;
  const int wm = (wave >> 1) * 64, wn = (wave & 1) * 64;
  const int srow = tid >> 3;                         // staging row 0..31
  const int swz = ((tid & 7) ^ (srow & 7)) * 8;      // pre-swizzled src col

  f32x4 acc[4][4] = {};

  const int rr = lane & 15;
  const int rx = (rr & 7) << 4;                      // read-side XOR (bytes)

  for (int k0 = 0; k0 < D_; k0 += 64) {
#pragma unroll
    for (int i = 0; i < 4; ++i) {
      int gr = bm + srow + i * 32;
      if (gr >= M) gr = M - 1;  // clamp: feeds only unstored C rows
      gload_lds16(A + (long)gr * D_ + k0 + swz, Asm + i * 2048 + wave * 512);
    }
#pragma unroll
    for (int i = 0; i < 4; ++i) {
      int gr = bn + srow + i * 32;
      gload_lds16(Bt + (long)gr * D_ + k0 + swz, Bsm + i * 2048 + wave * 512);
    }
    __syncthreads();
#pragma unroll
    for (int kk = 0; kk < 2; ++kk) {
      const int cb = kk * 64 + (lane >> 4) * 16;     // logical byte col
      const int cs = cb ^ rx;                        // swizzled byte col
      bf16x8 af[4], bfr[4];
#pragma unroll
      for (int i = 0; i < 4; ++i)
        af[i] = *(const bf16x8*)((const char*)Asm + (wm + i * 16 + rr) * 128 + cs);
#pragma unroll
      for (int j = 0; j < 4; ++j)
        bfr[j] = *(const bf16x8*)((const char*)Bsm + (wn + j * 16 + rr) * 128 + cs);
#pragma unroll
      for (int i = 0; i < 4; ++i)
#pragma unroll
        for (int j = 0; j < 4; ++j)
          acc[i][j] = __builtin_amdgcn_mfma_f32_16x16x32_bf16(
              af[i], bfr[j], acc[i][j], 0, 0, 0);
    }
    __syncthreads();
  }

  // epilogue
  float alpha = 1.f, beta = 0.f;
  if (WITH_SKIP) {
    float sv = skip[skip_idx];
    alpha = 1.f / (1.f + expf(-sv));
    beta = 1.f - alpha;
  }
  const int cr = (lane >> 4) * 4;
  const int cc = lane & 15;
  const int matu = (bn + wn) >> 9;
  const int wcb = (bn + wn) & 511;
  unsigned short* ob16 = (unsigned short*)outs.p[matu];
  float* ob32 = (float*)outs.p[0];
#pragma unroll
  for (int i = 0; i < 4; ++i) {
    int rowb = bm + wm + i * 16 + cr;
#pragma unroll
    for (int j = 0; j < 4; ++j) {
      int col = bn + wn + j * 16 + cc;
      float bb = bias[col];
#pragma unroll
      for (int r = 0; r < 4; ++r) {
        int row = rowb + r;
        if (row >= M) continue;
        float val = acc[i][j][r] * a_scale + bb;
        if (WITH_SKIP) val = val * alpha + Hres[(long)row * D_ + col] * beta;
        if (OUT_BF16)
          ob16[(long)row * D_ + wcb + j * 16 + cc] = f2bf(val);
        else
          ob32[(long)row * D_ + col] = val;
      }
    }
  }
}

// ---------------- launch ----------------
extern "C" void kernel_launch(void* const* d_in, const int* in_sizes, int n_in,
                              void* d_out, int out_size, void* d_ws, size_t ws_size,
                              hipStream_t stream) {
  const float* h_author = (const float*)d_in[0];
  const float* h_paper  = (const float*)d_in[1];
  const int* w_src = (const int*)d_in[2];
  const int* w_dst = (const int*)d_in[3];
  const int* c_src = (const int*)d_in[4];
  const int* c_dst = (const int*)d_in[5];
  const int* b_src = (const int*)d_in[6];
  const int* b_dst = (const int*)d_in[7];
  const float* Wk = (const float*)d_in[8];
  const float* bk = (const float*)d_in[9];
  const float* Wq = (const float*)d_in[10];
  const float* bq = (const float*)d_in[11];
  const float* Wv = (const float*)d_in[12];
  const float* bv = (const float*)d_in[13];
  const float* Wa = (const float*)d_in[14];
  const float* ba = (const float*)d_in[15];
  const float* rel_att = (const float*)d_in[16];
  const float* rel_msg = (const float*)d_in[17];
  const float* rel_pri = (const float*)d_in[18];
  const float* skip = (const float*)d_in[19];

  const int NA = in_sizes[0] / D_;
  const int NP = in_sizes[1] / D_;
  const int E  = in_sizes[2];
  const long nmax = (NA > NP) ? NA : NP;
  const int NT = 2 * NP + NA;        // concatenated CSR node count

  char* w = (char*)d_ws;
  auto alloc = [&](long bytes) {
    char* p = w;
    w += (bytes + 255) & ~255L;
    return p;
  };
  unsigned short* hA16 = (unsigned short*)alloc((long)NA * D_ * 2);
  unsigned short* hP16 = (unsigned short*)alloc((long)NP * D_ * 2);
  unsigned short* Pq   = (unsigned short*)alloc((long)NP * D_ * 2);
  unsigned short* Pkc  = (unsigned short*)alloc((long)NP * D_ * 2);
  unsigned short* Pvc  = (unsigned short*)alloc((long)NP * D_ * 2);
  unsigned short* Pkb  = (unsigned short*)alloc((long)NP * D_ * 2);
  unsigned short* Pvb  = (unsigned short*)alloc((long)NP * D_ * 2);
  unsigned short* Aq   = (unsigned short*)alloc((long)NA * D_ * 2);
  unsigned short* Akw  = (unsigned short*)alloc((long)NA * D_ * 2);
  unsigned short* Avw  = (unsigned short*)alloc((long)NA * D_ * 2);
  unsigned short* t16  = (unsigned short*)alloc(nmax * D_ * 2);
  unsigned short* BtP  = (unsigned short*)alloc((long)2560 * D_ * 2);
  unsigned short* BtA  = (unsigned short*)alloc((long)1536 * D_ * 2);
  float* bfP           = (float*)alloc(2560 * 4);
  float* bfA           = (float*)alloc(1536 * 4);
  unsigned short* Wa0t = (unsigned short*)alloc((long)D_ * D_ * 2);
  unsigned short* Wa1t = (unsigned short*)alloc((long)D_ * D_ * 2);
  int* degree          = (int*)alloc((long)NT * 4);
  int* starts          = (int*)alloc((long)NT * 4);
  int* cursor          = (int*)alloc((long)NT * 4);
  int* csr             = (int*)alloc((long)3 * E * 4);
  int* aux             = (int*)alloc(((long)NT / 256 + 2) * 4);

  const long WD = (long)D_ * D_;
  const long RS = (long)H_ * 64 * 64;
  const long SEG = (long)D_ * D_;

  auto fill = [&](float* p, float v, long n) {
    long b = (n + 255) / 256;
    int blocks = (int)(b > 4096 ? 4096 : b);
    fill_kernel<<<blocks, 256, 0, stream>>>(p, v, n);
  };
  auto cvt = [&](const float* in, unsigned short* out, long n) {
    long n8 = n / 8;
    long b = (n8 + 255) / 256;
    int blocks = (int)(b > 2048 ? 2048 : b);
    convert_bf16_kernel<<<blocks, 256, 0, stream>>>(in, out, n8);
  };

  float* out_a = (float*)d_out;
  float* out_p = out_a + (long)NA * D_;

  // ---- one-time conversions ----
  cvt(h_author, hA16, (long)NA * D_);
  cvt(h_paper, hP16, (long)NP * D_);

  // ---- CSR build (all 3 relations concatenated; papers x2, authors x1) ----
  fill((float*)degree, 0.f, NT);  // bit-pattern zero
  {
    int th = 3 * E;
    hist_kernel<<<(th + 255) / 256, 256, 0, stream>>>(w_dst, c_dst, b_dst,
                                                      degree, E, NP);
    int nb = (NT + 255) / 256;
    scan1_kernel<<<nb, 256, 0, stream>>>(degree, starts, aux, NT);
    scan2_kernel<<<1, 1024, 0, stream>>>(aux, nb);
    scan3_kernel<<<nb, 256, 0, stream>>>(starts, cursor, aux, NT);
    scatter_kernel<<<(th + 255) / 256, 256, 0, stream>>>(
        w_src, w_dst, c_src, c_dst, b_src, b_dst, cursor, csr, E, NP);
  }

  // ---- build fused Bt for papers: [q_p | k_cites | v_cites | k_wb | v_wb] ----
  transpose_bf16_kernel<<<D_, D_, 0, stream>>>(Wq + WD, BtP);
  copy_bias_kernel<<<1, D_, 0, stream>>>(bq + D_, bfP);
  fuse_weight_kernel<<<513, 512, 0, stream>>>(Wk + WD, bk + D_, rel_att + RS,
                                              BtP + SEG, bfP + 512);
  fuse_weight_kernel<<<513, 512, 0, stream>>>(Wv + WD, bv + D_, rel_msg + RS,
                                              BtP + 2 * SEG, bfP + 1024);
  fuse_weight_kernel<<<513, 512, 0, stream>>>(Wk + WD, bk + D_, rel_att + 2 * RS,
                                              BtP + 3 * SEG, bfP + 1536);
  fuse_weight_kernel<<<513, 512, 0, stream>>>(Wv + WD, bv + D_, rel_msg + 2 * RS,
                                              BtP + 4 * SEG, bfP + 2048);

  // ---- fused Bt for authors: [q_a | k_writes | v_writes] ----
  transpose_bf16_kernel<<<D_, D_, 0, stream>>>(Wq, BtA);
  copy_bias_kernel<<<1, D_, 0, stream>>>(bq, bfA);
  fuse_weight_kernel<<<513, 512, 0, stream>>>(Wk, bk, rel_att,
                                              BtA + SEG, bfA + 512);
  fuse_weight_kernel<<<513, 512, 0, stream>>>(Wv, bv, rel_msg,
                                              BtA + 2 * SEG, bfA + 1024);

  // output-projection weights
  transpose_bf16_kernel<<<D_, D_, 0, stream>>>(Wa, Wa0t);
  transpose_bf16_kernel<<<D_, D_, 0, stream>>>(Wa + WD, Wa1t);

  // ---- fused projection GEMMs ----
  {
    Outs o; o.p[0] = Pq; o.p[1] = Pkc; o.p[2] = Pvc; o.p[3] = Pkb; o.p[4] = Pvb;
    int gy = (NP + 127) / 128;
    gemm_mfma<1, 0><<<20 * gy, 256, 0, stream>>>(
        hP16, BtP, bfP, o, NP, 20, 1.f, nullptr, nullptr, 0);
  }
  {
    Outs o; o.p[0] = Aq; o.p[1] = Akw; o.p[2] = Avw; o.p[3] = Aq; o.p[4] = Aq;
    int gy = (NA + 127) / 128;
    gemm_mfma<1, 0><<<12 * gy, 256, 0, stream>>>(
        hA16, BtA, bfA, o, NA, 12, 1.f, nullptr, nullptr, 0);
  }

  // ---- paper attention: writes (k/v from authors) + cites (k/v from papers) ----
  {
    long th = (long)NP * 64;
    attn_kernel<1><<<(int)((th + 255) / 256), 256, 0, stream>>>(
        Pq, Akw, Avw, Pkc, Pvc, csr, starts, degree, 0, NP,
        rel_pri, 0, H_, t16, NP, 0.5f);
  }
  // ---- paper output ----
  {
    Outs o; o.p[0] = out_p; o.p[1] = o.p[2] = o.p[3] = o.p[4] = out_p;
    int gy = (NP + 127) / 128;
    gemm_mfma<0, 1><<<4 * gy, 256, 0, stream>>>(
        t16, Wa1t, ba + D_, o, NP, 4, 1.f, h_paper, skip, 1);
  }

  // ---- author attention: written_by (k/v from papers) ----
  {
    long th = (long)NA * 64;
    attn_kernel<0><<<(int)((th + 255) / 256), 256, 0, stream>>>(
        Aq, Pkb, Pvb, Pkb, Pvb, csr, starts, degree, 2 * NP, 2 * NP,
        rel_pri, 2 * H_, 2 * H_, t16, NA, 1.f);
  }
  // ---- author output ----
  {
    Outs o; o.p[0] = out_a; o.p[1] = o.p[2] = o.p[3] = o.p[4] = out_a;
    int gy = (NA + 127) / 128;
    gemm_mfma<0, 1><<<4 * gy, 256, 0, stream>>>(
        t16, Wa0t, ba, o, NA, 4, 1.f, h_author, skip, 0);
  }
}

// Round 6
// 985.506 us; speedup vs baseline: 5.2034x; 1.0795x over previous
//
#include <hip/hip_runtime.h>
#include <math.h>

#define D_ 512
#define H_ 8

typedef short bf16x8 __attribute__((ext_vector_type(8)));
typedef float f32x4 __attribute__((ext_vector_type(4)));

struct Outs { void* p[5]; };

__device__ __forceinline__ unsigned short f2bf(float x) {
  unsigned int u = __float_as_uint(x);
  unsigned int r = (u + 0x7fff + ((u >> 16) & 1)) >> 16;
  return (unsigned short)r;
}
__device__ __forceinline__ float bf2f(unsigned short b) {
  return __uint_as_float(((unsigned int)b) << 16);
}

// ---------------- utility ----------------
__global__ void fill_kernel(float* __restrict__ p, float v, long n) {
  long i = (long)blockIdx.x * blockDim.x + threadIdx.x;
  long st = (long)gridDim.x * blockDim.x;
  for (; i < n; i += st) p[i] = v;
}

__global__ void convert_bf16_kernel(const float* __restrict__ in,
                                    unsigned short* __restrict__ out, long n8) {
  long i = (long)blockIdx.x * blockDim.x + threadIdx.x;
  long st = (long)gridDim.x * blockDim.x;
  for (; i < n8; i += st) {
    float4 a = ((const float4*)in)[i * 2];
    float4 b = ((const float4*)in)[i * 2 + 1];
    bf16x8 o;
    o[0] = (short)f2bf(a.x); o[1] = (short)f2bf(a.y);
    o[2] = (short)f2bf(a.z); o[3] = (short)f2bf(a.w);
    o[4] = (short)f2bf(b.x); o[5] = (short)f2bf(b.y);
    o[6] = (short)f2bf(b.z); o[7] = (short)f2bf(b.w);
    ((bf16x8*)out)[i] = o;
  }
}

// Wt[n][k] = bf16(W[k][n]) for a 512x512 matrix
__global__ void transpose_bf16_kernel(const float* __restrict__ W,
                                      unsigned short* __restrict__ Wt) {
  int n = blockIdx.x;
  int k = threadIdx.x;
  Wt[(long)n * D_ + k] = f2bf(W[(long)k * D_ + n]);
}

__global__ void copy_bias_kernel(const float* __restrict__ in,
                                 float* __restrict__ out) {
  out[threadIdx.x] = in[threadIdx.x];
}

// ---------------- fused weight precompute (transposed bf16 out) ----------------
__global__ void fuse_weight_kernel(const float* __restrict__ Win,
                                   const float* __restrict__ bin,
                                   const float* __restrict__ rel,
                                   unsigned short* __restrict__ Wf,
                                   float* __restrict__ bf) {
  int row = blockIdx.x;            // 0..512 (c index; 512 => bias)
  int j = threadIdx.x;             // 0..511 (h*64+e)
  int h = j >> 6, e = j & 63;
  const float* src = (row < D_) ? (Win + (long)row * D_) : bin;
  const float* rl = rel + h * 64 * 64;
  float acc = 0.f;
#pragma unroll 16
  for (int d = 0; d < 64; ++d) acc = fmaf(src[h * 64 + d], rl[d * 64 + e], acc);
  if (row < D_) Wf[(long)j * D_ + row] = f2bf(acc);
  else bf[j] = acc;
}

// ---------------- CSR build: hist -> scan -> scatter ----------------
__global__ void hist_kernel(const int* __restrict__ w_dst,
                            const int* __restrict__ c_dst,
                            const int* __restrict__ b_dst,
                            int* __restrict__ degree, int E, int NP) {
  int i = blockIdx.x * blockDim.x + threadIdx.x;
  if (i >= 3 * E) return;
  int r = i / E, e = i - r * E;
  int d, base;
  if (r == 0)      { d = w_dst[e]; base = 0; }
  else if (r == 1) { d = c_dst[e]; base = NP; }
  else             { d = b_dst[e]; base = 2 * NP; }
  atomicAdd(degree + base + d, 1);
}

__global__ void scan1_kernel(const int* __restrict__ in, int* __restrict__ out,
                             int* __restrict__ aux, int n) {
  __shared__ int tmp[256];
  int t = threadIdx.x;
  int i = blockIdx.x * 256 + t;
  int v = (i < n) ? in[i] : 0;
  tmp[t] = v;
  __syncthreads();
#pragma unroll
  for (int d = 1; d < 256; d <<= 1) {
    int add = (t >= d) ? tmp[t - d] : 0;
    __syncthreads();
    tmp[t] += add;
    __syncthreads();
  }
  if (i < n) out[i] = tmp[t] - v;   // exclusive
  if (t == 255) aux[blockIdx.x] = tmp[255];
}

__global__ void scan2_kernel(int* __restrict__ aux, int nb) {
  __shared__ int tmp[1024];
  int t = threadIdx.x;
  int v = (t < nb) ? aux[t] : 0;
  tmp[t] = v;
  __syncthreads();
#pragma unroll
  for (int d = 1; d < 1024; d <<= 1) {
    int add = (t >= d) ? tmp[t - d] : 0;
    __syncthreads();
    tmp[t] += add;
    __syncthreads();
  }
  if (t < nb) aux[t] = tmp[t] - v;  // exclusive block offsets
}

__global__ void scan3_kernel(int* __restrict__ starts, int* __restrict__ cursor,
                             const int* __restrict__ aux, int n) {
  int i = blockIdx.x * 256 + threadIdx.x;
  if (i >= n) return;
  int s = starts[i] + aux[blockIdx.x];
  starts[i] = s;
  cursor[i] = s;
}

__global__ void scatter_kernel(const int* __restrict__ w_src, const int* __restrict__ w_dst,
                               const int* __restrict__ c_src, const int* __restrict__ c_dst,
                               const int* __restrict__ b_src, const int* __restrict__ b_dst,
                               int* __restrict__ cursor, int* __restrict__ csr,
                               int E, int NP) {
  int i = blockIdx.x * blockDim.x + threadIdx.x;
  if (i >= 3 * E) return;
  int r = i / E, e = i - r * E;
  int s, d, base;
  if (r == 0)      { s = w_src[e]; d = w_dst[e]; base = 0; }
  else if (r == 1) { s = c_src[e]; d = c_dst[e]; base = NP; }
  else             { s = b_src[e]; d = b_dst[e]; base = 2 * NP; }
  int pos = atomicAdd(cursor + base + d, 1);
  csr[pos] = s;
}

// ---------------- fused per-node edge attention (flash-style) ----------------
template <int TWO_LISTS>
__global__ __launch_bounds__(256) void attn_kernel(
    const unsigned short* __restrict__ q,
    const unsigned short* __restrict__ k0, const unsigned short* __restrict__ v0,
    const unsigned short* __restrict__ k1, const unsigned short* __restrict__ v1,
    const int* __restrict__ csr, const int* __restrict__ starts,
    const int* __restrict__ degree, int base0, int base1,
    const float* __restrict__ pri, int poff0, int poff1,
    unsigned short* __restrict__ out, int n_nodes, float outscale) {
  int gw = (int)(((long)blockIdx.x * blockDim.x + threadIdx.x) >> 6);
  if (gw >= n_nodes) return;
  int lane = threadIdx.x & 63;
  int h = lane >> 3, off = (lane & 7) << 3;
  const long rowoff = (long)gw * D_ + h * 64 + off;
  bf16x8 qv = *(const bf16x8*)(q + rowoff);
  float qf[8];
#pragma unroll
  for (int r = 0; r < 8; ++r) qf[r] = bf2f((unsigned short)qv[r]);

  float res[8] = {};

  auto process = [&](const unsigned short* K, const unsigned short* V,
                     int base, float ps) {
    int st = starts[base + gw], dg = degree[base + gw];
    float m = -INFINITY, l = 0.f;
    float acc[8] = {};
    for (int i = 0; i < dg; ++i) {
      int s = csr[st + i];
      const long ro = (long)s * D_ + h * 64 + off;
      bf16x8 kv = *(const bf16x8*)(K + ro);
      bf16x8 vv = *(const bf16x8*)(V + ro);
      float dot = 0.f;
#pragma unroll
      for (int r = 0; r < 8; ++r)
        dot = fmaf(qf[r], bf2f((unsigned short)kv[r]), dot);
      dot += __shfl_xor(dot, 1);
      dot += __shfl_xor(dot, 2);
      dot += __shfl_xor(dot, 4);
      float sc = dot * ps;
      float mn = fmaxf(m, sc);
      float scale = __expf(m - mn);   // m=-inf first edge -> 0
      float p = __expf(sc - mn);
      l = l * scale + p;
#pragma unroll
      for (int r = 0; r < 8; ++r)
        acc[r] = acc[r] * scale + p * bf2f((unsigned short)vv[r]);
      m = mn;
    }
    if (l > 0.f) {
      float inv = 1.f / l;
#pragma unroll
      for (int r = 0; r < 8; ++r) res[r] += acc[r] * inv;
    }
  };

  process(k0, v0, base0, pri[poff0 + h] * 0.125f);
  if (TWO_LISTS) process(k1, v1, base1, pri[poff1 + h] * 0.125f);

  bf16x8 o;
#pragma unroll
  for (int r = 0; r < 8; ++r) o[r] = (short)f2bf(res[r] * outscale);
  *(bf16x8*)(out + rowoff) = o;
}

// ---------------- MFMA GEMM: 256x256 tile, 2-deep counted-vmcnt pipeline -----
// T3+T4: prologue stages K-tiles 0,1; each iter waits vmcnt(8) (tile t done,
// tile t+1 stays in flight), raw s_barrier (no vmcnt(0) drain!), ds_read+MFMA
// (T5 setprio), raw s_barrier, then stages tile t+2 into the freed buffer.
// T2 swizzle: LDS linear, pre-swizzled global source col + XOR on ds_read.
__device__ __forceinline__ void gload_lds16(const void* g, void* l) {
  __builtin_amdgcn_global_load_lds(
      (const __attribute__((address_space(1))) void*)g,
      (__attribute__((address_space(3))) void*)l, 16, 0, 0);
}

template <int OUT_BF16, int WITH_SKIP>
__global__ __launch_bounds__(512, 2) void gemm_mfma(
    const unsigned short* __restrict__ A,
    const unsigned short* __restrict__ Bt,
    const float* __restrict__ bias,
    Outs outs, int M, int GX, float a_scale,
    const float* __restrict__ Hres,
    const float* __restrict__ skip, int skip_idx) {
  __shared__ unsigned short Asm[2][256 * 64];   // 64 KiB
  __shared__ unsigned short Bsm[2][256 * 64];   // 64 KiB

  // bijective XCD-aware swizzle (m204); N-tile fastest within a chunk.
  const int nwg = gridDim.x;
  const int orig = blockIdx.x;
  const int q8 = nwg >> 3, r8 = nwg & 7;
  const int xcd = orig & 7, pos = orig >> 3;
  const int wgid =
      (xcd < r8 ? xcd * (q8 + 1) : r8 * (q8 + 1) + (xcd - r8) * q8) + pos;
  const int bm = (wgid / GX) * 256;
  const int bn = (wgid % GX) * 256;

  const int tid = threadIdx.x;                  // 0..511
  const int wave = tid >> 6, lane = tid & 63;
  const int wm = (wave >> 2) * 128;             // 2 M-waves
  const int wn = (wave & 3) * 64;               // 4 N-waves
  const int srow = tid >> 3;                    // staging row 0..63 per issue
  const int swz = ((tid & 7) ^ (srow & 7)) * 8; // pre-swizzled src col (elems)

  f32x4 acc[8][4] = {};

  const int rr = lane & 15;
  const int rx = (rr & 7) << 4;                 // read-side XOR (bytes)

  auto STAGE = [&](int buf, int kt) {
    const int k0 = kt * 64;
#pragma unroll
    for (int i = 0; i < 4; ++i) {
      int gr = bm + srow + i * 64;
      if (gr >= M) gr = M - 1;  // clamp: feeds only unstored C rows
      gload_lds16(A + (long)gr * D_ + k0 + swz, &Asm[buf][i * 4096 + wave * 512]);
    }
#pragma unroll
    for (int i = 0; i < 4; ++i) {
      int gr = bn + srow + i * 64;
      gload_lds16(Bt + (long)gr * D_ + k0 + swz, &Bsm[buf][i * 4096 + wave * 512]);
    }
  };

  // prologue: stage K-tiles 0 and 1 (8 loads/thread each)
  STAGE(0, 0);
  STAGE(1, 1);

#pragma unroll
  for (int t = 0; t < 8; ++t) {
    const int p = t & 1;
    // tile t's 8 loads complete; tile t+1's 8 may remain in flight
    if (t == 7) asm volatile("s_waitcnt vmcnt(0)" ::: "memory");
    else        asm volatile("s_waitcnt vmcnt(8)" ::: "memory");
    __builtin_amdgcn_s_barrier();
    asm volatile("" ::: "memory");

#pragma unroll
    for (int kk = 0; kk < 2; ++kk) {
      const int cb = kk * 64 + (lane >> 4) * 16;   // logical byte col
      const int cs = cb ^ rx;                      // swizzled byte col
      bf16x8 af[8], bfr[4];
#pragma unroll
      for (int mi = 0; mi < 8; ++mi)
        af[mi] = *(const bf16x8*)((const char*)&Asm[p][0] +
                                  (wm + mi * 16 + rr) * 128 + cs);
#pragma unroll
      for (int nj = 0; nj < 4; ++nj)
        bfr[nj] = *(const bf16x8*)((const char*)&Bsm[p][0] +
                                   (wn + nj * 16 + rr) * 128 + cs);
      __builtin_amdgcn_s_setprio(1);
#pragma unroll
      for (int mi = 0; mi < 8; ++mi)
#pragma unroll
        for (int nj = 0; nj < 4; ++nj)
          acc[mi][nj] = __builtin_amdgcn_mfma_f32_16x16x32_bf16(
              af[mi], bfr[nj], acc[mi][nj], 0, 0, 0);
      __builtin_amdgcn_s_setprio(0);
    }

    asm volatile("" ::: "memory");
    __builtin_amdgcn_s_barrier();   // all waves done reading buf p
    asm volatile("" ::: "memory");
    if (t + 2 < 8) STAGE(p, t + 2); // refill freed buffer; stays in flight
  }

  // epilogue
  float alpha = 1.f, beta = 0.f;
  if (WITH_SKIP) {
    float sv = skip[skip_idx];
    alpha = 1.f / (1.f + expf(-sv));
    beta = 1.f - alpha;
  }
  const int cr = (lane >> 4) * 4;
  const int cc = lane & 15;
  const int matu = (bn + wn) >> 9;
  const int wcb = (bn + wn) & 511;
  unsigned short* ob16 = (unsigned short*)outs.p[matu];
  float* ob32 = (float*)outs.p[0];
#pragma unroll
  for (int mi = 0; mi < 8; ++mi) {
    int rowb = bm + wm + mi * 16 + cr;
#pragma unroll
    for (int nj = 0; nj < 4; ++nj) {
      int col = bn + wn + nj * 16 + cc;
      float bb = bias[col];
#pragma unroll
      for (int r = 0; r < 4; ++r) {
        int row = rowb + r;
        if (row >= M) continue;
        float val = acc[mi][nj][r] * a_scale + bb;
        if (WITH_SKIP) val = val * alpha + Hres[(long)row * D_ + col] * beta;
        if (OUT_BF16)
          ob16[(long)row * D_ + wcb + nj * 16 + cc] = f2bf(val);
        else
          ob32[(long)row * D_ + col] = val;
      }
    }
  }
}

// ---------------- launch ----------------
extern "C" void kernel_launch(void* const* d_in, const int* in_sizes, int n_in,
                              void* d_out, int out_size, void* d_ws, size_t ws_size,
                              hipStream_t stream) {
  const float* h_author = (const float*)d_in[0];
  const float* h_paper  = (const float*)d_in[1];
  const int* w_src = (const int*)d_in[2];
  const int* w_dst = (const int*)d_in[3];
  const int* c_src = (const int*)d_in[4];
  const int* c_dst = (const int*)d_in[5];
  const int* b_src = (const int*)d_in[6];
  const int* b_dst = (const int*)d_in[7];
  const float* Wk = (const float*)d_in[8];
  const float* bk = (const float*)d_in[9];
  const float* Wq = (const float*)d_in[10];
  const float* bq = (const float*)d_in[11];
  const float* Wv = (const float*)d_in[12];
  const float* bv = (const float*)d_in[13];
  const float* Wa = (const float*)d_in[14];
  const float* ba = (const float*)d_in[15];
  const float* rel_att = (const float*)d_in[16];
  const float* rel_msg = (const float*)d_in[17];
  const float* rel_pri = (const float*)d_in[18];
  const float* skip = (const float*)d_in[19];

  const int NA = in_sizes[0] / D_;
  const int NP = in_sizes[1] / D_;
  const int E  = in_sizes[2];
  const long nmax = (NA > NP) ? NA : NP;
  const int NT = 2 * NP + NA;        // concatenated CSR node count

  char* w = (char*)d_ws;
  auto alloc = [&](long bytes) {
    char* p = w;
    w += (bytes + 255) & ~255L;
    return p;
  };
  unsigned short* hA16 = (unsigned short*)alloc((long)NA * D_ * 2);
  unsigned short* hP16 = (unsigned short*)alloc((long)NP * D_ * 2);
  unsigned short* Pq   = (unsigned short*)alloc((long)NP * D_ * 2);
  unsigned short* Pkc  = (unsigned short*)alloc((long)NP * D_ * 2);
  unsigned short* Pvc  = (unsigned short*)alloc((long)NP * D_ * 2);
  unsigned short* Pkb  = (unsigned short*)alloc((long)NP * D_ * 2);
  unsigned short* Pvb  = (unsigned short*)alloc((long)NP * D_ * 2);
  unsigned short* Aq   = (unsigned short*)alloc((long)NA * D_ * 2);
  unsigned short* Akw  = (unsigned short*)alloc((long)NA * D_ * 2);
  unsigned short* Avw  = (unsigned short*)alloc((long)NA * D_ * 2);
  unsigned short* t16  = (unsigned short*)alloc(nmax * D_ * 2);
  unsigned short* BtP  = (unsigned short*)alloc((long)2560 * D_ * 2);
  unsigned short* BtA  = (unsigned short*)alloc((long)1536 * D_ * 2);
  float* bfP           = (float*)alloc(2560 * 4);
  float* bfA           = (float*)alloc(1536 * 4);
  unsigned short* Wa0t = (unsigned short*)alloc((long)D_ * D_ * 2);
  unsigned short* Wa1t = (unsigned short*)alloc((long)D_ * D_ * 2);
  int* degree          = (int*)alloc((long)NT * 4);
  int* starts          = (int*)alloc((long)NT * 4);
  int* cursor          = (int*)alloc((long)NT * 4);
  int* csr             = (int*)alloc((long)3 * E * 4);
  int* aux             = (int*)alloc(((long)NT / 256 + 2) * 4);

  const long WD = (long)D_ * D_;
  const long RS = (long)H_ * 64 * 64;
  const long SEG = (long)D_ * D_;

  auto fill = [&](float* p, float v, long n) {
    long b = (n + 255) / 256;
    int blocks = (int)(b > 4096 ? 4096 : b);
    fill_kernel<<<blocks, 256, 0, stream>>>(p, v, n);
  };
  auto cvt = [&](const float* in, unsigned short* out, long n) {
    long n8 = n / 8;
    long b = (n8 + 255) / 256;
    int blocks = (int)(b > 2048 ? 2048 : b);
    convert_bf16_kernel<<<blocks, 256, 0, stream>>>(in, out, n8);
  };

  float* out_a = (float*)d_out;
  float* out_p = out_a + (long)NA * D_;

  // ---- one-time conversions ----
  cvt(h_author, hA16, (long)NA * D_);
  cvt(h_paper, hP16, (long)NP * D_);

  // ---- CSR build (all 3 relations concatenated; papers x2, authors x1) ----
  fill((float*)degree, 0.f, NT);  // bit-pattern zero
  {
    int th = 3 * E;
    hist_kernel<<<(th + 255) / 256, 256, 0, stream>>>(w_dst, c_dst, b_dst,
                                                      degree, E, NP);
    int nb = (NT + 255) / 256;
    scan1_kernel<<<nb, 256, 0, stream>>>(degree, starts, aux, NT);
    scan2_kernel<<<1, 1024, 0, stream>>>(aux, nb);
    scan3_kernel<<<nb, 256, 0, stream>>>(starts, cursor, aux, NT);
    scatter_kernel<<<(th + 255) / 256, 256, 0, stream>>>(
        w_src, w_dst, c_src, c_dst, b_src, b_dst, cursor, csr, E, NP);
  }

  // ---- build fused Bt for papers: [q_p | k_cites | v_cites | k_wb | v_wb] ----
  transpose_bf16_kernel<<<D_, D_, 0, stream>>>(Wq + WD, BtP);
  copy_bias_kernel<<<1, D_, 0, stream>>>(bq + D_, bfP);
  fuse_weight_kernel<<<513, 512, 0, stream>>>(Wk + WD, bk + D_, rel_att + RS,
                                              BtP + SEG, bfP + 512);
  fuse_weight_kernel<<<513, 512, 0, stream>>>(Wv + WD, bv + D_, rel_msg + RS,
                                              BtP + 2 * SEG, bfP + 1024);
  fuse_weight_kernel<<<513, 512, 0, stream>>>(Wk + WD, bk + D_, rel_att + 2 * RS,
                                              BtP + 3 * SEG, bfP + 1536);
  fuse_weight_kernel<<<513, 512, 0, stream>>>(Wv + WD, bv + D_, rel_msg + 2 * RS,
                                              BtP + 4 * SEG, bfP + 2048);

  // ---- fused Bt for authors: [q_a | k_writes | v_writes] ----
  transpose_bf16_kernel<<<D_, D_, 0, stream>>>(Wq, BtA);
  copy_bias_kernel<<<1, D_, 0, stream>>>(bq, bfA);
  fuse_weight_kernel<<<513, 512, 0, stream>>>(Wk, bk, rel_att,
                                              BtA + SEG, bfA + 512);
  fuse_weight_kernel<<<513, 512, 0, stream>>>(Wv, bv, rel_msg,
                                              BtA + 2 * SEG, bfA + 1024);

  // output-projection weights
  transpose_bf16_kernel<<<D_, D_, 0, stream>>>(Wa, Wa0t);
  transpose_bf16_kernel<<<D_, D_, 0, stream>>>(Wa + WD, Wa1t);

  // ---- fused projection GEMMs (256x256 tiles) ----
  {
    Outs o; o.p[0] = Pq; o.p[1] = Pkc; o.p[2] = Pvc; o.p[3] = Pkb; o.p[4] = Pvb;
    int gy = (NP + 255) / 256;
    gemm_mfma<1, 0><<<10 * gy, 512, 0, stream>>>(
        hP16, BtP, bfP, o, NP, 10, 1.f, nullptr, nullptr, 0);
  }
  {
    Outs o; o.p[0] = Aq; o.p[1] = Akw; o.p[2] = Avw; o.p[3] = Aq; o.p[4] = Aq;
    int gy = (NA + 255) / 256;
    gemm_mfma<1, 0><<<6 * gy, 512, 0, stream>>>(
        hA16, BtA, bfA, o, NA, 6, 1.f, nullptr, nullptr, 0);
  }

  // ---- paper attention: writes (k/v from authors) + cites (k/v from papers) ----
  {
    long th = (long)NP * 64;
    attn_kernel<1><<<(int)((th + 255) / 256), 256, 0, stream>>>(
        Pq, Akw, Avw, Pkc, Pvc, csr, starts, degree, 0, NP,
        rel_pri, 0, H_, t16, NP, 0.5f);
  }
  // ---- paper output ----
  {
    Outs o; o.p[0] = out_p; o.p[1] = o.p[2] = o.p[3] = o.p[4] = out_p;
    int gy = (NP + 255) / 256;
    gemm_mfma<0, 1><<<2 * gy, 512, 0, stream>>>(
        t16, Wa1t, ba + D_, o, NP, 2, 1.f, h_paper, skip, 1);
  }

  // ---- author attention: written_by (k/v from papers) ----
  {
    long th = (long)NA * 64;
    attn_kernel<0><<<(int)((th + 255) / 256), 256, 0, stream>>>(
        Aq, Pkb, Pvb, Pkb, Pvb, csr, starts, degree, 2 * NP, 2 * NP,
        rel_pri, 2 * H_, 2 * H_, t16, NA, 1.f);
  }
  // ---- author output ----
  {
    Outs o; o.p[0] = out_a; o.p[1] = o.p[2] = o.p[3] = o.p[4] = out_a;
    int gy = (NA + 255) / 256;
    gemm_mfma<0, 1><<<2 * gy, 512, 0, stream>>>(
        t16, Wa0t, ba, o, NA, 2, 1.f, h_author, skip, 0);
  }
}